// Round 15
// baseline (1319.671 us; speedup 1.0000x reference)
//
#include <hip/hip_runtime.h>
#include <hip/hip_bf16.h>
#include <math.h>

#define BATCH  16384
#define NCATS  16
#define VOCABN 1000
#define DIMD   64
#define SHARED_E 10
#define INDIVE 54
#define CONTN  16
#define FLATN  1040   // NCATS*DIMD + CONTN
#define H1N    4160
#define H2N    2080
#define KP1    1088   // FLATN padded to mult of 64
#define NP1    4224   // H1N padded to mult of 128
#define KP2    4224   // = NP1 (GEMM2 K)
#define NP2    2176   // H2N padded to mult of 128
#define EPSV   1e-5f

typedef __attribute__((ext_vector_type(8))) short bf16x8;
typedef __attribute__((ext_vector_type(4))) float f32x4;

__device__ __forceinline__ float gelu_f(float x) {
    return 0.5f * x * (1.0f + erff(x * 0.70710678118654752440f));
}
__device__ __forceinline__ float wsum(float v) {
#pragma unroll
    for (int o = 32; o > 0; o >>= 1) v += __shfl_xor(v, o, 64);
    return v;
}
__device__ __forceinline__ short f2bf_s(float a) {
    __hip_bfloat16 x = __float2bfloat16(a);
    return *reinterpret_cast<short*>(&x);
}
__device__ __forceinline__ unsigned int packbf(float a, float b) {
    __hip_bfloat16 x = __float2bfloat16(a), y = __float2bfloat16(b);
    unsigned short ux = *reinterpret_cast<unsigned short*>(&x);
    unsigned short uy = *reinterpret_cast<unsigned short*>(&y);
    return (unsigned)ux | ((unsigned)uy << 16);
}
__device__ __forceinline__ float bf_lo(unsigned int u) { return __uint_as_float(u << 16); }
__device__ __forceinline__ float bf_hi(unsigned int u) { return __uint_as_float(u & 0xffff0000u); }
// async global->LDS, 16B per lane; LDS dest is wave-uniform base + lane*16 (m97)
__device__ __forceinline__ void gload16(const void* g, void* l) {
    __builtin_amdgcn_global_load_lds(
        (const __attribute__((address_space(1))) void*)g,
        (__attribute__((address_space(3))) void*)l, 16, 0, 0);
}

// ---------------- token build: xflat[:, 0:1024] (chunk-local rows) ----------------
__global__ __launch_bounds__(256) void build_tokens(
    const int* __restrict__ x_cat, const float* __restrict__ shared_emb,
    const float* __restrict__ emb, float* __restrict__ xflat)
{
    int idx = blockIdx.x * 256 + threadIdx.x;      // mc*1024 total
    int b = idx >> 10, r = idx & 1023;
    int c = r >> 6, d = r & 63;
    float v;
    if (d < SHARED_E) v = shared_emb[d];
    else              v = emb[((size_t)c * VOCABN + x_cat[b * NCATS + c]) * INDIVE + (d - SHARED_E)];
    xflat[(size_t)b * FLATN + r] = v;
}

// ---------------- cont projection: xflat[:, 1024:1040] ----------------
__global__ __launch_bounds__(256) void cont_proj(
    const float* __restrict__ x_cont, const float* __restrict__ cw,
    const float* __restrict__ cb, float* __restrict__ xflat)
{
    int idx = blockIdx.x * 256 + threadIdx.x;      // mc*16 total
    int b = idx >> 4, j = idx & 15;
    float acc = cb[j];
#pragma unroll
    for (int k = 0; k < 16; ++k) acc += x_cont[b * 16 + k] * cw[k * 16 + j];
    xflat[(size_t)b * FLATN + 1024 + j] = acc;
}

// ---------------- micro encoder (MFMA): 8 samples/block (16 rows), 1 wave ----------------
__global__ __launch_bounds__(64) void micro_enc_mfma(
    float* __restrict__ xflat, const short* __restrict__ wT,
    const float* __restrict__ ln1w, const float* __restrict__ ln1b,
    const float* __restrict__ ln2w, const float* __restrict__ ln2b,
    const float* __restrict__ b1, const float* __restrict__ b2)
{
    __shared__ __align__(16) float Xr[16][68];
    __shared__ __align__(16) short XN[16][72];
    __shared__ __align__(16) short KVb[16][136];  // K cols 0-63, V 64-127; later ff1
    __shared__ __align__(16) short Qb[16][72];

    int lane = threadIdx.x;
    int b0 = blockIdx.x * 8;

    {   // load: row r = s*2+t  <-  xflat[(b0+s)][t*64 + c]
        int r = lane >> 2, c0 = (lane & 3) * 16;
        const float* gx = xflat + (size_t)(b0 + (r >> 1)) * FLATN + (r & 1) * 64 + c0;
#pragma unroll
        for (int u = 0; u < 4; ++u) *(float4*)&Xr[r][c0 + u * 4] = *(const float4*)(gx + u * 4);
    }
    __syncthreads();

    int fr = lane & 15, fk = lane >> 4;
    int rb = 4 * fk;
    float prevM[2] = {0.f, 0.f};

    for (int p = 0; p < 2; ++p) {
        const short* lq  = wT + p * 49152;
        const short* lo  = lq + 12288;
        const short* lf1 = lo + 4096;
        const short* lf2 = lf1 + 16384;
        const float* l1w = ln1w + p * 64; const float* l1b = ln1b + p * 64;
        const float* l2w = ln2w + p * 64; const float* l2b = ln2b + p * 64;
        const float* fb1 = b1 + p * 256;  const float* fb2 = b2 + p * 64;

        {   // LN1 -> XN (register-blocked)
            int r = lane >> 2, c = (lane & 3) * 16;
            float4 va[4];
#pragma unroll
            for (int u = 0; u < 4; ++u) va[u] = *(const float4*)&Xr[r][c + u * 4];
            float s = 0.f, s2 = 0.f;
#pragma unroll
            for (int u = 0; u < 4; ++u) {
                s  += va[u].x + va[u].y + va[u].z + va[u].w;
                s2 += va[u].x * va[u].x + va[u].y * va[u].y + va[u].z * va[u].z + va[u].w * va[u].w;
            }
            s  += __shfl_xor(s, 1, 64);  s2 += __shfl_xor(s2, 1, 64);
            s  += __shfl_xor(s, 2, 64);  s2 += __shfl_xor(s2, 2, 64);
            float m = s * (1.f / 64.f);
            float var = s2 * (1.f / 64.f) - m * m;
            float rstd = rsqrtf(var + EPSV);
            unsigned pk[8];
#pragma unroll
            for (int u = 0; u < 4; ++u) {
                float4 wv4 = *(const float4*)(l1w + c + u * 4);
                float4 bv4 = *(const float4*)(l1b + c + u * 4);
                pk[2 * u]     = packbf((va[u].x - m) * rstd * wv4.x + bv4.x,
                                       (va[u].y - m) * rstd * wv4.y + bv4.y);
                pk[2 * u + 1] = packbf((va[u].z - m) * rstd * wv4.z + bv4.z,
                                       (va[u].w - m) * rstd * wv4.w + bv4.w);
            }
            *(uint4*)&XN[r][c]     = *(uint4*)&pk[0];
            *(uint4*)&XN[r][c + 8] = *(uint4*)&pk[4];
        }
        __syncthreads();

        {   // qkv MFMA: nf 0-3 -> Qb, nf 4-11 -> KVb
            bf16x8 a0 = *(const bf16x8*)&XN[fr][fk * 8];
            bf16x8 a1 = *(const bf16x8*)&XN[fr][fk * 8 + 32];
#pragma unroll
            for (int nf = 0; nf < 12; ++nf) {
                const short* bp = lq + (nf * 16 + fr) * 64 + fk * 8;
                bf16x8 bv0 = *(const bf16x8*)bp;
                bf16x8 bv1 = *(const bf16x8*)(bp + 32);
                f32x4 acc = {};
                acc = __builtin_amdgcn_mfma_f32_16x16x32_bf16(a0, bv0, acc, 0, 0, 0);
                acc = __builtin_amdgcn_mfma_f32_16x16x32_bf16(a1, bv1, acc, 0, 0, 0);
                int cc = nf * 16 + fr;
#pragma unroll
                for (int rr = 0; rr < 4; ++rr) {
                    if (nf < 4) Qb[rb + rr][cc] = f2bf_s(acc[rr]);
                    else        KVb[rb + rr][cc - 64] = f2bf_s(acc[rr]);
                }
            }
        }
        __syncthreads();

        {   // attention: lane = (s=lane>>3, h=(lane>>1)&3, qi=lane&1); 2 keys, registers
            int s_ = lane >> 3, h = (lane >> 1) & 3, qi = lane & 1;
            int qrow = s_ * 2 + qi;
            float q[16];
            {
                const unsigned* qp = (const unsigned*)&Qb[qrow][h * 16];
#pragma unroll
                for (int e = 0; e < 8; ++e) { q[2 * e] = bf_lo(qp[e]); q[2 * e + 1] = bf_hi(qp[e]); }
            }
            float sc[2];
#pragma unroll
            for (int j = 0; j < 2; ++j) {
                const unsigned* kp = (const unsigned*)&KVb[s_ * 2 + j][h * 16];
                float a = 0.f;
#pragma unroll
                for (int e = 0; e < 8; ++e)
                    a += q[2 * e] * bf_lo(kp[e]) + q[2 * e + 1] * bf_hi(kp[e]);
                a = a * 0.25f + prevM[j];
                prevM[j] = a;
                sc[j] = a;
            }
            float mx = fmaxf(sc[0], sc[1]);
            float e0 = expf(sc[0] - mx), e1 = expf(sc[1] - mx);
            float inv = 1.f / (e0 + e1);
            float p0 = e0 * inv, p1 = e1 * inv;
            const unsigned* v0 = (const unsigned*)&KVb[s_ * 2 + 0][64 + h * 16];
            const unsigned* v1 = (const unsigned*)&KVb[s_ * 2 + 1][64 + h * 16];
            unsigned* op = (unsigned*)&XN[qrow][h * 16];
#pragma unroll
            for (int e = 0; e < 8; ++e) {
                unsigned ua = v0[e], ub = v1[e];
                float olo = p0 * bf_lo(ua) + p1 * bf_lo(ub);
                float ohi = p0 * bf_hi(ua) + p1 * bf_hi(ub);
                op[e] = packbf(olo, ohi);
            }
        }
        __syncthreads();

        {   // out proj + residual
            bf16x8 a0 = *(const bf16x8*)&XN[fr][fk * 8];
            bf16x8 a1 = *(const bf16x8*)&XN[fr][fk * 8 + 32];
#pragma unroll
            for (int nf = 0; nf < 4; ++nf) {
                const short* bp = lo + (nf * 16 + fr) * 64 + fk * 8;
                bf16x8 bv0 = *(const bf16x8*)bp;
                bf16x8 bv1 = *(const bf16x8*)(bp + 32);
                f32x4 acc = {};
                acc = __builtin_amdgcn_mfma_f32_16x16x32_bf16(a0, bv0, acc, 0, 0, 0);
                acc = __builtin_amdgcn_mfma_f32_16x16x32_bf16(a1, bv1, acc, 0, 0, 0);
                int cc = nf * 16 + fr;
#pragma unroll
                for (int rr = 0; rr < 4; ++rr) Xr[rb + rr][cc] += acc[rr];
            }
        }
        __syncthreads();

        {   // LN2 -> XN (register-blocked)
            int r = lane >> 2, c = (lane & 3) * 16;
            float4 va[4];
#pragma unroll
            for (int u = 0; u < 4; ++u) va[u] = *(const float4*)&Xr[r][c + u * 4];
            float s = 0.f, s2 = 0.f;
#pragma unroll
            for (int u = 0; u < 4; ++u) {
                s  += va[u].x + va[u].y + va[u].z + va[u].w;
                s2 += va[u].x * va[u].x + va[u].y * va[u].y + va[u].z * va[u].z + va[u].w * va[u].w;
            }
            s  += __shfl_xor(s, 1, 64);  s2 += __shfl_xor(s2, 1, 64);
            s  += __shfl_xor(s, 2, 64);  s2 += __shfl_xor(s2, 2, 64);
            float m = s * (1.f / 64.f);
            float var = s2 * (1.f / 64.f) - m * m;
            float rstd = rsqrtf(var + EPSV);
            unsigned pk[8];
#pragma unroll
            for (int u = 0; u < 4; ++u) {
                float4 wv4 = *(const float4*)(l2w + c + u * 4);
                float4 bv4 = *(const float4*)(l2b + c + u * 4);
                pk[2 * u]     = packbf((va[u].x - m) * rstd * wv4.x + bv4.x,
                                       (va[u].y - m) * rstd * wv4.y + bv4.y);
                pk[2 * u + 1] = packbf((va[u].z - m) * rstd * wv4.z + bv4.z,
                                       (va[u].w - m) * rstd * wv4.w + bv4.w);
            }
            *(uint4*)&XN[r][c]     = *(uint4*)&pk[0];
            *(uint4*)&XN[r][c + 8] = *(uint4*)&pk[4];
        }
        __syncthreads();

        {   // FFN: ff1 halves -> KVb, ff2 acc in regs
            bf16x8 a0 = *(const bf16x8*)&XN[fr][fk * 8];
            bf16x8 a1 = *(const bf16x8*)&XN[fr][fk * 8 + 32];
            f32x4 facc[4] = {};
#pragma unroll
            for (int half = 0; half < 2; ++half) {
#pragma unroll
                for (int nf = 0; nf < 8; ++nf) {
                    int ng = half * 128 + nf * 16;
                    const short* bp = lf1 + (ng + fr) * 64 + fk * 8;
                    bf16x8 bv0 = *(const bf16x8*)bp;
                    bf16x8 bv1 = *(const bf16x8*)(bp + 32);
                    f32x4 acc = {};
                    acc = __builtin_amdgcn_mfma_f32_16x16x32_bf16(a0, bv0, acc, 0, 0, 0);
                    acc = __builtin_amdgcn_mfma_f32_16x16x32_bf16(a1, bv1, acc, 0, 0, 0);
                    int cc = nf * 16 + fr;
                    float bias1 = fb1[ng + fr];
#pragma unroll
                    for (int rr = 0; rr < 4; ++rr)
                        KVb[rb + rr][cc] = f2bf_s(gelu_f(acc[rr] + bias1));
                }
                __syncthreads();
                bf16x8 fa[4];
#pragma unroll
                for (int kf = 0; kf < 4; ++kf)
                    fa[kf] = *(const bf16x8*)&KVb[fr][kf * 32 + fk * 8];
#pragma unroll
                for (int nf = 0; nf < 4; ++nf) {
                    const short* bp = lf2 + (nf * 16 + fr) * 256 + half * 128 + fk * 8;
#pragma unroll
                    for (int kf = 0; kf < 4; ++kf)
                        facc[nf] = __builtin_amdgcn_mfma_f32_16x16x32_bf16(
                            fa[kf], *(const bf16x8*)(bp + kf * 32), facc[nf], 0, 0, 0);
                }
                __syncthreads();
            }
#pragma unroll
            for (int nf = 0; nf < 4; ++nf) {
                int cc = nf * 16 + fr;
                float bias2 = fb2[cc];
#pragma unroll
                for (int rr = 0; rr < 4; ++rr) Xr[rb + rr][cc] += facc[nf][rr] + bias2;
            }
        }
        __syncthreads();
    }

    {   // store back
        int r = lane >> 2, c0 = (lane & 3) * 16;
        float* gx = xflat + (size_t)(b0 + (r >> 1)) * FLATN + (r & 1) * 64 + c0;
#pragma unroll
        for (int u = 0; u < 4; ++u) *(float4*)(gx + u * 4) = *(const float4*)&Xr[r][c0 + u * 4];
    }
}

// ---------------- macro encoder (MFMA attn): 1 sample / block, FOUR waves ----------------
// r15: two-stage register preload of this wave's weight fragments (qkv/outproj at layer
// start, ff1/ff2 after out-proj) -> weight-load latency off the phase critical path.
__global__ __launch_bounds__(256) void macro_enc_mfma(
    float* __restrict__ xflat, __hip_bfloat16* __restrict__ Abf,
    const short* __restrict__ wT,
    const float* __restrict__ ln1w, const float* __restrict__ ln1b,
    const float* __restrict__ ln2w, const float* __restrict__ ln2b,
    const float* __restrict__ b1, const float* __restrict__ b2)
{
    __shared__ __align__(16) float Xr[16][68];
    __shared__ __align__(16) short XN[16][72];
    __shared__ __align__(16) short Qb[16][72];
    __shared__ __align__(16) short Kb[16][72];
    __shared__ __align__(16) short VT[16][72];   // VT[d][h*16 + token]

    int tid = threadIdx.x;
    int lane = tid & 63, w = tid >> 6;
    int b = blockIdx.x;

    {   // load residual: 256 threads x 4 floats
        int r = tid >> 4, c0 = (tid & 15) * 4;
        const float* gx = xflat + (size_t)b * FLATN + r * 64 + c0;
        *(float4*)&Xr[r][c0] = *(const float4*)gx;
    }
    __syncthreads();

    int fr = lane & 15, fk = lane >> 4;
    int rb = 4 * fk;
    f32x4 prevA = {};   // this wave's head: h = w

    for (int p = 0; p < 2; ++p) {
        const short* lq  = wT + p * 49152;
        const short* lo  = lq + 12288;
        const short* lf1 = lo + 4096;
        const short* lf2 = lf1 + 16384;
        const float* l1w = ln1w + p * 64; const float* l1b = ln1b + p * 64;
        const float* l2w = ln2w + p * 64; const float* l2b = ln2b + p * 64;
        const float* fb1 = b1 + p * 256;  const float* fb2 = b2 + p * 64;

        // ---- stage-1 preload: qkv (nf = w*3..w*3+2) + outproj (nf = w) fragments ----
        bf16x8 wq0[3], wq1[3], wo0, wo1;
#pragma unroll
        for (int nn = 0; nn < 3; ++nn) {
            const short* bp = lq + ((w * 3 + nn) * 16 + fr) * 64 + fk * 8;
            wq0[nn] = *(const bf16x8*)bp;
            wq1[nn] = *(const bf16x8*)(bp + 32);
        }
        {
            const short* bp = lo + (w * 16 + fr) * 64 + fk * 8;
            wo0 = *(const bf16x8*)bp;
            wo1 = *(const bf16x8*)(bp + 32);
        }

        {   // LN1 -> XN (register-blocked)
            int r = w * 4 + (lane >> 4);
            int c = (lane & 15) * 4;
            float4 v = *(const float4*)&Xr[r][c];
            float s  = v.x + v.y + v.z + v.w;
            float s2 = v.x * v.x + v.y * v.y + v.z * v.z + v.w * v.w;
#pragma unroll
            for (int o = 1; o < 16; o <<= 1) {
                s  += __shfl_xor(s, o, 64);
                s2 += __shfl_xor(s2, o, 64);
            }
            float m = s * (1.f / 64.f);
            float var = s2 * (1.f / 64.f) - m * m;
            float rstd = rsqrtf(var + EPSV);
            float4 wv4 = *(const float4*)(l1w + c);
            float4 bv4 = *(const float4*)(l1b + c);
            unsigned pk0 = packbf((v.x - m) * rstd * wv4.x + bv4.x,
                                  (v.y - m) * rstd * wv4.y + bv4.y);
            unsigned pk1 = packbf((v.z - m) * rstd * wv4.z + bv4.z,
                                  (v.w - m) * rstd * wv4.w + bv4.w);
            unsigned long long pk = (unsigned long long)pk0 | ((unsigned long long)pk1 << 32);
            *(unsigned long long*)&XN[r][c] = pk;
        }
        __syncthreads();

        {   // qkv MFMA: wave w does nf = w*3 .. w*3+2; uses preloaded frags
            bf16x8 a0 = *(const bf16x8*)&XN[fr][fk * 8];
            bf16x8 a1 = *(const bf16x8*)&XN[fr][fk * 8 + 32];
#pragma unroll
            for (int nn = 0; nn < 3; ++nn) {
                int nf = w * 3 + nn;
                f32x4 acc = {};
                acc = __builtin_amdgcn_mfma_f32_16x16x32_bf16(a0, wq0[nn], acc, 0, 0, 0);
                acc = __builtin_amdgcn_mfma_f32_16x16x32_bf16(a1, wq1[nn], acc, 0, 0, 0);
                if (nf < 8) {
#pragma unroll
                    for (int rr = 0; rr < 4; ++rr) {
                        short sv = f2bf_s(acc[rr]);
                        if (nf < 4) Qb[rb + rr][nf * 16 + fr] = sv;
                        else        Kb[rb + rr][(nf - 4) * 16 + fr] = sv;
                    }
                } else {
                    unsigned long long pkv =
                        (unsigned long long)packbf(acc[0], acc[1]) |
                        ((unsigned long long)packbf(acc[2], acc[3]) << 32);
                    *(unsigned long long*)&VT[fr][(nf - 8) * 16 + rb] = pkv;
                }
            }
        }
        __syncthreads();

        {   // MFMA attention: wave w handles head h = w
            bf16x8 zero8 = {};
            int h = w;
            bf16x8 ka = zero8, qa = zero8, va = zero8;
            if (fk < 2) {
                ka = *(const bf16x8*)&Kb[fr][h * 16 + fk * 8];
                qa = *(const bf16x8*)&Qb[fr][h * 16 + fk * 8];
                va = *(const bf16x8*)&VT[fr][h * 16 + fk * 8];
            }
            f32x4 s = {};
            s = __builtin_amdgcn_mfma_f32_16x16x32_bf16(ka, qa, s, 0, 0, 0);
#pragma unroll
            for (int rr = 0; rr < 4; ++rr) {
                s[rr] = s[rr] * 0.25f + prevA[rr];
                prevA[rr] = s[rr];
            }
            float m = fmaxf(fmaxf(s[0], s[1]), fmaxf(s[2], s[3]));
            m = fmaxf(m, __shfl_xor(m, 16, 64));
            m = fmaxf(m, __shfl_xor(m, 32, 64));
            float e0 = expf(s[0] - m), e1 = expf(s[1] - m);
            float e2 = expf(s[2] - m), e3 = expf(s[3] - m);
            float sum = e0 + e1 + e2 + e3;
            sum += __shfl_xor(sum, 16, 64);
            sum += __shfl_xor(sum, 32, 64);
            float inv = 1.f / sum;
            int pk0 = (int)packbf(e0 * inv, e1 * inv);
            int pk1 = (int)packbf(e2 * inv, e3 * inv);
            int s1 = fr + (((2 * fk) & 3) << 4);
            int s2 = fr + (((2 * fk + 1) & 3) << 4);
            int d0 = __shfl(pk0, s1, 64), d1 = __shfl(pk1, s1, 64);
            int d2 = __shfl(pk0, s2, 64), d3 = __shfl(pk1, s2, 64);
            bf16x8 pa = zero8;
            if (fk < 2) {
                union { int i[4]; bf16x8 v; } u;
                u.i[0] = d0; u.i[1] = d1; u.i[2] = d2; u.i[3] = d3;
                pa = u.v;
            }
            f32x4 o = {};
            o = __builtin_amdgcn_mfma_f32_16x16x32_bf16(pa, va, o, 0, 0, 0);
#pragma unroll
            for (int rr = 0; rr < 4; ++rr)
                XN[4 * fk + rr][h * 16 + fr] = f2bf_s(o[rr]);
        }
        __syncthreads();

        {   // out proj + residual: wave w does nf = w (preloaded frags)
            bf16x8 a0 = *(const bf16x8*)&XN[fr][fk * 8];
            bf16x8 a1 = *(const bf16x8*)&XN[fr][fk * 8 + 32];
            f32x4 acc = {};
            acc = __builtin_amdgcn_mfma_f32_16x16x32_bf16(a0, wo0, acc, 0, 0, 0);
            acc = __builtin_amdgcn_mfma_f32_16x16x32_bf16(a1, wo1, acc, 0, 0, 0);
            int cc = w * 16 + fr;
#pragma unroll
            for (int rr = 0; rr < 4; ++rr) Xr[rb + rr][cc] += acc[rr];
        }

        // ---- stage-2 preload: ff1 (nf = w*2..w*2+1, both halves) + ff2 (nf = w) ----
        bf16x8 wf1a[2][2], wf1b[2][2], wf2[2][4];
#pragma unroll
        for (int half = 0; half < 2; ++half) {
#pragma unroll
            for (int nn = 0; nn < 2; ++nn) {
                int ng = half * 128 + (w * 2 + nn) * 16;
                const short* bp = lf1 + (ng + fr) * 64 + fk * 8;
                wf1a[half][nn] = *(const bf16x8*)bp;
                wf1b[half][nn] = *(const bf16x8*)(bp + 32);
            }
            const short* bp2 = lf2 + (w * 16 + fr) * 256 + half * 128 + fk * 8;
#pragma unroll
            for (int kf = 0; kf < 4; ++kf)
                wf2[half][kf] = *(const bf16x8*)(bp2 + kf * 32);
        }
        __syncthreads();

        {   // LN2 -> XN (register-blocked)
            int r = w * 4 + (lane >> 4);
            int c = (lane & 15) * 4;
            float4 v = *(const float4*)&Xr[r][c];
            float s  = v.x + v.y + v.z + v.w;
            float s2 = v.x * v.x + v.y * v.y + v.z * v.z + v.w * v.w;
#pragma unroll
            for (int o = 1; o < 16; o <<= 1) {
                s  += __shfl_xor(s, o, 64);
                s2 += __shfl_xor(s2, o, 64);
            }
            float m = s * (1.f / 64.f);
            float var = s2 * (1.f / 64.f) - m * m;
            float rstd = rsqrtf(var + EPSV);
            float4 wv4 = *(const float4*)(l2w + c);
            float4 bv4 = *(const float4*)(l2b + c);
            unsigned pk0 = packbf((v.x - m) * rstd * wv4.x + bv4.x,
                                  (v.y - m) * rstd * wv4.y + bv4.y);
            unsigned pk1 = packbf((v.z - m) * rstd * wv4.z + bv4.z,
                                  (v.w - m) * rstd * wv4.w + bv4.w);
            unsigned long long pk = (unsigned long long)pk0 | ((unsigned long long)pk1 << 32);
            *(unsigned long long*)&XN[r][c] = pk;
        }
        __syncthreads();

        {   // FFN: ff1 wave w nf = w*2..w*2+1 (->Qb/Kb); ff2 nf = w (preloaded frags)
            bf16x8 a0 = *(const bf16x8*)&XN[fr][fk * 8];
            bf16x8 a1 = *(const bf16x8*)&XN[fr][fk * 8 + 32];
            f32x4 facc = {};
#pragma unroll
            for (int half = 0; half < 2; ++half) {
#pragma unroll
                for (int nn = 0; nn < 2; ++nn) {
                    int nf = w * 2 + nn;
                    int ng = half * 128 + nf * 16;
                    f32x4 acc = {};
                    acc = __builtin_amdgcn_mfma_f32_16x16x32_bf16(a0, wf1a[half][nn], acc, 0, 0, 0);
                    acc = __builtin_amdgcn_mfma_f32_16x16x32_bf16(a1, wf1b[half][nn], acc, 0, 0, 0);
                    int cc = nf * 16 + fr;
                    float bias1 = fb1[ng + fr];
#pragma unroll
                    for (int rr = 0; rr < 4; ++rr) {
                        short sv = f2bf_s(gelu_f(acc[rr] + bias1));
                        if (cc < 64) Qb[rb + rr][cc] = sv;
                        else         Kb[rb + rr][cc - 64] = sv;
                    }
                }
                __syncthreads();
                bf16x8 fa[4];
                fa[0] = *(const bf16x8*)&Qb[fr][fk * 8];
                fa[1] = *(const bf16x8*)&Qb[fr][32 + fk * 8];
                fa[2] = *(const bf16x8*)&Kb[fr][fk * 8];
                fa[3] = *(const bf16x8*)&Kb[fr][32 + fk * 8];
#pragma unroll
                for (int kf = 0; kf < 4; ++kf)
                    facc = __builtin_amdgcn_mfma_f32_16x16x32_bf16(
                        fa[kf], wf2[half][kf], facc, 0, 0, 0);
                __syncthreads();
            }
            {
                int cc = w * 16 + fr;
                float bias2 = fb2[cc];
#pragma unroll
                for (int rr = 0; rr < 4; ++rr) Xr[rb + rr][cc] += facc[rr] + bias2;
            }
        }
        __syncthreads();
    }

    // store residual (fp32) + bf16 token part of Abf
    {
        int r = tid >> 4, c0 = (tid & 15) * 4;
        float* gx = xflat + (size_t)b * FLATN + r * 64 + c0;
        *(float4*)gx = *(const float4*)&Xr[r][c0];
        unsigned int pk[2];
        pk[0] = packbf(Xr[r][c0], Xr[r][c0 + 1]);
        pk[1] = packbf(Xr[r][c0 + 2], Xr[r][c0 + 3]);
        unsigned int* ga = (unsigned int*)(Abf + (size_t)b * KP1 + r * 64 + c0);
        ga[0] = pk[0]; ga[1] = pk[1];
    }
    if (tid < 64) {
        float v = (tid < CONTN) ? xflat[(size_t)b * FLATN + 1024 + tid] : 0.f;
        Abf[(size_t)b * KP1 + 1024 + tid] = __float2bfloat16(v);
    }
}

// ---------------- transpose + convert: W[K][N] fp32 -> Wt[Np][Kp] bf16 (zero-padded) ----
__global__ __launch_bounds__(256) void transpose_conv(
    const float* __restrict__ src, __hip_bfloat16* __restrict__ dst,
    int K, int N, int Kp, int Np)
{
    __shared__ float T[32][33];
    int k0 = blockIdx.y * 32, n0 = blockIdx.x * 32;
    int tn = threadIdx.x & 31, tk = threadIdx.x >> 5;
#pragma unroll
    for (int r = 0; r < 4; ++r) {
        int k = k0 + tk + r * 8, n = n0 + tn;
        T[tk + r * 8][tn] = (k < K && n < N) ? src[(size_t)k * N + n] : 0.f;
    }
    __syncthreads();
#pragma unroll
    for (int r = 0; r < 4; ++r) {
        int n = n0 + tk + r * 8, k = k0 + tn;
        dst[(size_t)n * Kp + k] = __float2bfloat16(T[tn][tk + r * 8]);
    }
}

// ---------------- bf16 MFMA GEMM: m97 structure (single 32KB buffer, 2 barriers/K-step)
// + T2 both-sides swizzle (conflict-free). 3 blocks/CU (launch_bounds 3 waves/SIMD).
// MODE 1: C[M][Np] bf16 gelu via slot-swizzled LDS restage (coalesced 128B stores).
// MODE 2: partials[row][bx] = sum_cols gelu(.)*w3[col] (fused final dot).
template <int MODE>
__global__ __launch_bounds__(256, 3) void gemm_mfma(
    const __hip_bfloat16* __restrict__ A, const __hip_bfloat16* __restrict__ Bt,
    const float* __restrict__ bias, int bias_n,
    __hip_bfloat16* __restrict__ Cbf, const float* __restrict__ w3,
    float* __restrict__ partials, int Np, int Kp)
{
    __shared__ __align__(16) short LDSbuf[16384];   // 32KB: A 8192 | B 8192 shorts

    int tid = threadIdx.x;
    int lane = tid & 63, wave = tid >> 6;

    // bijective XCD swizzle (m204)
    int nbx = gridDim.x;
    int nwg = nbx * gridDim.y;
    int wgid = blockIdx.y * nbx + blockIdx.x;
    int q = nwg >> 3, r = nwg & 7;
    int xcd = wgid & 7, loc = wgid >> 3;
    int sw = (xcd < r ? xcd * (q + 1) : r * (q + 1) + (xcd - r) * q) + loc;
    int bm = (sw / nbx) * 128, bx = sw % nbx, bn = bx * 128;

    // staging addresses: lane l -> row (l>>3), k-slot (l&7)^(l>>3)  [T2 pre-swizzle]
    int lrow8 = lane >> 3;
    int lk8sw = ((lane & 7) ^ lrow8) * 8;
    const __hip_bfloat16* Ag = A  + (size_t)(bm + wave * 32 + lrow8) * Kp + lk8sw;
    const __hip_bfloat16* Bg = Bt + (size_t)(bn + wave * 32 + lrow8) * Kp + lk8sw;
    short* Al = LDSbuf + wave * 32 * 64;
    short* Bl = Al + 8192;

    int wm = (wave >> 1) * 64, wn = (wave & 1) * 64;
    int lrow = lane & 15, lk = lane >> 4;
    int key = lane & 7;                     // = (row&7) for this lane's fragment rows

    f32x4 acc[4][4] = {};
    int nt = Kp >> 6;

    for (int t = 0; t < nt; ++t) {
        int k0 = t << 6;
        __syncthreads();                    // prev tile's reads complete
#pragma unroll
        for (int it = 0; it < 4; ++it) {
            gload16(Ag + (size_t)(it * 8) * Kp + k0, Al + it * 8 * 64);
            gload16(Bg + (size_t)(it * 8) * Kp + k0, Bl + it * 8 * 64);
        }
        __syncthreads();                    // vmcnt(0) drain -> tile ready
#pragma unroll
        for (int ks = 0; ks < 2; ++ks) {
            int so = ((ks * 4 + lk) ^ key) * 8;     // swizzled slot offset (shorts)
            bf16x8 af[4], bf[4];
#pragma unroll
            for (int i = 0; i < 4; ++i) af[i] = *(const bf16x8*)(LDSbuf + (wm + i * 16 + lrow) * 64 + so);
#pragma unroll
            for (int j = 0; j < 4; ++j) bf[j] = *(const bf16x8*)(LDSbuf + 8192 + (wn + j * 16 + lrow) * 64 + so);
#pragma unroll
            for (int i = 0; i < 4; ++i)
#pragma unroll
                for (int j = 0; j < 4; ++j)
                    acc[i][j] = __builtin_amdgcn_mfma_f32_16x16x32_bf16(af[i], bf[j], acc[i][j], 0, 0, 0);
        }
    }
    __syncthreads();   // all LDS reads done; buffer reusable for epilogue

    if (MODE == 1) {
        // slot-swizzled LDS restage -> full-line coalesced bf16 stores
        short* Cs = LDSbuf;                 // [128][128] shorts = 32KB
#pragma unroll
        for (int j = 0; j < 4; ++j) {
            int cl = wn + j * 16 + lrow;
            float bv = (bn + cl < bias_n) ? bias[bn + cl] : 0.f;
#pragma unroll
            for (int i = 0; i < 4; ++i) {
#pragma unroll
                for (int rr = 0; rr < 4; ++rr) {
                    int rl = wm + i * 16 + 4 * lk + rr;
                    int pos = ((((cl >> 3) ^ (rl & 7)) << 3) | (cl & 7));
                    Cs[rl * 128 + pos] = f2bf_s(gelu_f(acc[i][j][rr] + bv));
                }
            }
        }
        __syncthreads();
        int rloc = tid >> 1, half = tid & 1;
        int4* dst = (int4*)(Cbf + (size_t)(bm + rloc) * Np + bn + half * 64);
#pragma unroll
        for (int u = 0; u < 8; ++u) {
            int slot = half * 8 + (u ^ (rloc & 7));
            dst[u] = *(const int4*)&Cs[rloc * 128 + slot * 8];
        }
    } else {
        // fused w3 reduction
        float rs[16];
#pragma unroll
        for (int t = 0; t < 16; ++t) rs[t] = 0.f;
#pragma unroll
        for (int j = 0; j < 4; ++j) {
            int gcol = bn + wn + j * 16 + lrow;
            float bv  = (gcol < bias_n) ? bias[gcol] : 0.f;
            float w3v = (gcol < H2N) ? w3[gcol] : 0.f;
#pragma unroll
            for (int i = 0; i < 4; ++i)
#pragma unroll
                for (int rr = 0; rr < 4; ++rr)
                    rs[i * 4 + rr] += gelu_f(acc[i][j][rr] + bv) * w3v;
        }
#pragma unroll
        for (int o = 1; o < 16; o <<= 1)
#pragma unroll
            for (int t = 0; t < 16; ++t) rs[t] += __shfl_xor(rs[t], o, 64);
        float* pr = (float*)LDSbuf;         // [128][2]
        if (lrow == 0) {
#pragma unroll
            for (int i = 0; i < 4; ++i)
#pragma unroll
                for (int rr = 0; rr < 4; ++rr)
                    pr[(wm + i * 16 + 4 * lk + rr) * 2 + (wave & 1)] = rs[i * 4 + rr];
        }
        __syncthreads();
        if (tid < 128)
            partials[(size_t)(bm + tid) * nbx + bx] = pr[tid * 2] + pr[tid * 2 + 1];
    }
}

// ---------------- logits = b3 + sum over N-tiles of partials ----------------
__global__ __launch_bounds__(256) void reduce_partials(
    const float* __restrict__ partials, const float* __restrict__ b3,
    float* __restrict__ out, int n, int nbx)
{
    int b = blockIdx.x * 256 + threadIdx.x;
    if (b >= n) return;
    float s = b3[0];
    for (int x = 0; x < nbx; ++x) s += partials[(size_t)b * nbx + x];
    out[b] = s;
}

extern "C" void kernel_launch(void* const* d_in, const int* in_sizes, int n_in,
                              void* d_out, int out_size, void* d_ws, size_t ws_size,
                              hipStream_t stream)
{
    const int*   x_cat      = (const int*)  d_in[0];
    const float* x_cont     = (const float*)d_in[1];
    const float* shared_emb = (const float*)d_in[2];
    const float* emb        = (const float*)d_in[3];
    const float* mi_qkv  = (const float*)d_in[4];
    const float* mi_out  = (const float*)d_in[5];
    const float* mi_ln1w = (const float*)d_in[6];
    const float* mi_ln1b = (const float*)d_in[7];
    const float* mi_ln2w = (const float*)d_in[8];
    const float* mi_ln2b = (const float*)d_in[9];
    const float* mi_w1   = (const float*)d_in[10];
    const float* mi_b1   = (const float*)d_in[11];
    const float* mi_w2   = (const float*)d_in[12];
    const float* mi_b2   = (const float*)d_in[13];
    const float* ma_qkv  = (const float*)d_in[14];
    const float* ma_out  = (const float*)d_in[15];
    const float* ma_ln1w = (const float*)d_in[16];
    const float* ma_ln1b = (const float*)d_in[17];
    const float* ma_ln2w = (const float*)d_in[18];
    const float* ma_ln2b = (const float*)d_in[19];
    const float* ma_w1   = (const float*)d_in[20];
    const float* ma_b1   = (const float*)d_in[21];
    const float* ma_w2   = (const float*)d_in[22];
    const float* ma_b2   = (const float*)d_in[23];
    const float* cont_w  = (const float*)d_in[24];
    const float* cont_b  = (const float*)d_in[25];
    const float* w1      = (const float*)d_in[26];
    const float* b1      = (const float*)d_in[27];
    const float* w2      = (const float*)d_in[28];
    const float* b2      = (const float*)d_in[29];
    const float* w3      = (const float*)d_in[30];
    const float* b3      = (const float*)d_in[31];
    float* out = (float*)d_out;

    const int NBX2 = NP2 / 128;          // 17 N-tiles in GEMM2
    const size_t ENC_SH = 4 * 49152;     // ma L0, ma L1, mi L0, mi L1
    const size_t FIXED = ((size_t)NP1 * KP1 + (size_t)NP2 * KP2 + ENC_SH) * 2;
    const size_t PER_ROW = (size_t)NP1 * 2 + (size_t)FLATN * 4 + (size_t)KP1 * 2 + (size_t)NBX2 * 4;
    size_t avail = (ws_size > FIXED) ? ws_size - FIXED : 0;
    long long chl = (long long)(avail / PER_ROW);
    int CH = (int)((chl / 128) * 128);
    if (CH > BATCH) CH = BATCH;
    if (CH < 128) CH = 128;

    char* p = (char*)d_ws;
    __hip_bfloat16* w1T = (__hip_bfloat16*)p; p += (size_t)NP1 * KP1 * 2;
    __hip_bfloat16* w2T = (__hip_bfloat16*)p; p += (size_t)NP2 * KP2 * 2;
    __hip_bfloat16* encT = (__hip_bfloat16*)p; p += ENC_SH * 2;
    __hip_bfloat16* h1  = (__hip_bfloat16*)p; p += (size_t)CH * NP1 * 2;
    float* xflat = (float*)p;                 p += (size_t)CH * FLATN * 4;
    __hip_bfloat16* Abf = (__hip_bfloat16*)p; p += (size_t)CH * KP1 * 2;
    float* partials = (float*)p;

    transpose_conv<<<dim3(NP1 / 32, KP1 / 32), 256, 0, stream>>>(w1, w1T, FLATN, H1N, KP1, NP1);
    transpose_conv<<<dim3(NP2 / 32, KP2 / 32), 256, 0, stream>>>(w2, w2T, H1N, H2N, KP2, NP2);

    // encoder weights -> bf16 [N][K] per layer: qkvT | outT | ff1T | ff2T
    const float* enc_qkv[2] = {ma_qkv, mi_qkv};
    const float* enc_out[2] = {ma_out, mi_out};
    const float* enc_w1[2]  = {ma_w1,  mi_w1};
    const float* enc_w2[2]  = {ma_w2,  mi_w2};
    for (int grp = 0; grp < 2; ++grp) {
        for (int pl = 0; pl < 2; ++pl) {
            __hip_bfloat16* base = encT + (size_t)(grp * 2 + pl) * 49152;
            transpose_conv<<<dim3(192 / 32, 64 / 32), 256, 0, stream>>>(
                enc_qkv[grp] + pl * 64 * 192, base, 64, 192, 64, 192);
            transpose_conv<<<dim3(64 / 32, 64 / 32), 256, 0, stream>>>(
                enc_out[grp] + pl * 64 * 64, base + 12288, 64, 64, 64, 64);
            transpose_conv<<<dim3(256 / 32, 64 / 32), 256, 0, stream>>>(
                enc_w1[grp] + pl * 64 * 256, base + 16384, 64, 256, 64, 256);
            transpose_conv<<<dim3(64 / 32, 256 / 32), 256, 0, stream>>>(
                enc_w2[grp] + pl * 256 * 64, base + 32768, 256, 64, 256, 64);
        }
    }

    for (int m0 = 0; m0 < BATCH; m0 += CH) {
        int mc = BATCH - m0 < CH ? BATCH - m0 : CH;   // multiple of 128

        build_tokens<<<(mc * 1024) / 256, 256, 0, stream>>>(
            x_cat + (size_t)m0 * NCATS, shared_emb, emb, xflat);
        cont_proj<<<(mc * 16) / 256, 256, 0, stream>>>(
            x_cont + (size_t)m0 * CONTN, cont_w, cont_b, xflat);
        micro_enc_mfma<<<mc / 8, 64, 0, stream>>>(
            xflat, (const short*)encT + 2 * 49152, mi_ln1w, mi_ln1b, mi_ln2w, mi_ln2b, mi_b1, mi_b2);
        macro_enc_mfma<<<mc, 256, 0, stream>>>(
            xflat, Abf, (const short*)encT, ma_ln1w, ma_ln1b, ma_ln2w, ma_ln2b, ma_b1, ma_b2);

        gemm_mfma<1><<<dim3(NP1 / 128, mc / 128), 256, 0, stream>>>(
            Abf, w1T, b1, H1N, h1, nullptr, nullptr, NP1, KP1);
        gemm_mfma<2><<<dim3(NBX2, mc / 128), 256, 0, stream>>>(
            h1, w2T, b2, H2N, nullptr, w3, partials, NP2, KP2);

        reduce_partials<<<(mc + 255) / 256, 256, 0, stream>>>(partials, b3, out + m0, mc, NBX2);
    }
}

// Round 16
// 1230.209 us; speedup vs baseline: 1.0727x; 1.0727x over previous
//
#include <hip/hip_runtime.h>
#include <hip/hip_bf16.h>
#include <math.h>

#define BATCH  16384
#define NCATS  16
#define VOCABN 1000
#define DIMD   64
#define SHARED_E 10
#define INDIVE 54
#define CONTN  16
#define FLATN  1040   // NCATS*DIMD + CONTN
#define H1N    4160
#define H2N    2080
#define KP1    1088   // FLATN padded to mult of 64
#define NP1    4224   // H1N padded to mult of 128
#define KP2    4224   // = NP1 (GEMM2 K)
#define NP2    2176   // H2N padded to mult of 128
#define EPSV   1e-5f

typedef __attribute__((ext_vector_type(8))) short bf16x8;
typedef __attribute__((ext_vector_type(4))) float f32x4;

__device__ __forceinline__ float gelu_f(float x) {
    return 0.5f * x * (1.0f + erff(x * 0.70710678118654752440f));
}
__device__ __forceinline__ float wsum(float v) {
#pragma unroll
    for (int o = 32; o > 0; o >>= 1) v += __shfl_xor(v, o, 64);
    return v;
}
__device__ __forceinline__ short f2bf_s(float a) {
    __hip_bfloat16 x = __float2bfloat16(a);
    return *reinterpret_cast<short*>(&x);
}
__device__ __forceinline__ unsigned int packbf(float a, float b) {
    __hip_bfloat16 x = __float2bfloat16(a), y = __float2bfloat16(b);
    unsigned short ux = *reinterpret_cast<unsigned short*>(&x);
    unsigned short uy = *reinterpret_cast<unsigned short*>(&y);
    return (unsigned)ux | ((unsigned)uy << 16);
}
__device__ __forceinline__ float bf_lo(unsigned int u) { return __uint_as_float(u << 16); }
__device__ __forceinline__ float bf_hi(unsigned int u) { return __uint_as_float(u & 0xffff0000u); }
// async global->LDS, 16B per lane; LDS dest is wave-uniform base + lane*16 (m97)
__device__ __forceinline__ void gload16(const void* g, void* l) {
    __builtin_amdgcn_global_load_lds(
        (const __attribute__((address_space(1))) void*)g,
        (__attribute__((address_space(3))) void*)l, 16, 0, 0);
}

// ---------------- token build: xflat[:, 0:1024] (chunk-local rows) ----------------
__global__ __launch_bounds__(256) void build_tokens(
    const int* __restrict__ x_cat, const float* __restrict__ shared_emb,
    const float* __restrict__ emb, float* __restrict__ xflat)
{
    int idx = blockIdx.x * 256 + threadIdx.x;      // mc*1024 total
    int b = idx >> 10, r = idx & 1023;
    int c = r >> 6, d = r & 63;
    float v;
    if (d < SHARED_E) v = shared_emb[d];
    else              v = emb[((size_t)c * VOCABN + x_cat[b * NCATS + c]) * INDIVE + (d - SHARED_E)];
    xflat[(size_t)b * FLATN + r] = v;
}

// ---------------- cont projection: xflat[:, 1024:1040] ----------------
__global__ __launch_bounds__(256) void cont_proj(
    const float* __restrict__ x_cont, const float* __restrict__ cw,
    const float* __restrict__ cb, float* __restrict__ xflat)
{
    int idx = blockIdx.x * 256 + threadIdx.x;      // mc*16 total
    int b = idx >> 4, j = idx & 15;
    float acc = cb[j];
#pragma unroll
    for (int k = 0; k < 16; ++k) acc += x_cont[b * 16 + k] * cw[k * 16 + j];
    xflat[(size_t)b * FLATN + 1024 + j] = acc;
}

// ---------------- micro encoder (MFMA): 8 samples/block (16 rows), 1 wave ----------------
__global__ __launch_bounds__(64) void micro_enc_mfma(
    float* __restrict__ xflat, const short* __restrict__ wT,
    const float* __restrict__ ln1w, const float* __restrict__ ln1b,
    const float* __restrict__ ln2w, const float* __restrict__ ln2b,
    const float* __restrict__ b1, const float* __restrict__ b2)
{
    __shared__ __align__(16) float Xr[16][68];
    __shared__ __align__(16) short XN[16][72];
    __shared__ __align__(16) short KVb[16][136];  // K cols 0-63, V 64-127; later ff1
    __shared__ __align__(16) short Qb[16][72];

    int lane = threadIdx.x;
    int b0 = blockIdx.x * 8;

    {   // load: row r = s*2+t  <-  xflat[(b0+s)][t*64 + c]
        int r = lane >> 2, c0 = (lane & 3) * 16;
        const float* gx = xflat + (size_t)(b0 + (r >> 1)) * FLATN + (r & 1) * 64 + c0;
#pragma unroll
        for (int u = 0; u < 4; ++u) *(float4*)&Xr[r][c0 + u * 4] = *(const float4*)(gx + u * 4);
    }
    __syncthreads();

    int fr = lane & 15, fk = lane >> 4;
    int rb = 4 * fk;
    float prevM[2] = {0.f, 0.f};

    for (int p = 0; p < 2; ++p) {
        const short* lq  = wT + p * 49152;
        const short* lo  = lq + 12288;
        const short* lf1 = lo + 4096;
        const short* lf2 = lf1 + 16384;
        const float* l1w = ln1w + p * 64; const float* l1b = ln1b + p * 64;
        const float* l2w = ln2w + p * 64; const float* l2b = ln2b + p * 64;
        const float* fb1 = b1 + p * 256;  const float* fb2 = b2 + p * 64;

        {   // LN1 -> XN (register-blocked)
            int r = lane >> 2, c = (lane & 3) * 16;
            float4 va[4];
#pragma unroll
            for (int u = 0; u < 4; ++u) va[u] = *(const float4*)&Xr[r][c + u * 4];
            float s = 0.f, s2 = 0.f;
#pragma unroll
            for (int u = 0; u < 4; ++u) {
                s  += va[u].x + va[u].y + va[u].z + va[u].w;
                s2 += va[u].x * va[u].x + va[u].y * va[u].y + va[u].z * va[u].z + va[u].w * va[u].w;
            }
            s  += __shfl_xor(s, 1, 64);  s2 += __shfl_xor(s2, 1, 64);
            s  += __shfl_xor(s, 2, 64);  s2 += __shfl_xor(s2, 2, 64);
            float m = s * (1.f / 64.f);
            float var = s2 * (1.f / 64.f) - m * m;
            float rstd = rsqrtf(var + EPSV);
            unsigned pk[8];
#pragma unroll
            for (int u = 0; u < 4; ++u) {
                float4 wv4 = *(const float4*)(l1w + c + u * 4);
                float4 bv4 = *(const float4*)(l1b + c + u * 4);
                pk[2 * u]     = packbf((va[u].x - m) * rstd * wv4.x + bv4.x,
                                       (va[u].y - m) * rstd * wv4.y + bv4.y);
                pk[2 * u + 1] = packbf((va[u].z - m) * rstd * wv4.z + bv4.z,
                                       (va[u].w - m) * rstd * wv4.w + bv4.w);
            }
            *(uint4*)&XN[r][c]     = *(uint4*)&pk[0];
            *(uint4*)&XN[r][c + 8] = *(uint4*)&pk[4];
        }
        __syncthreads();

        {   // qkv MFMA: nf 0-3 -> Qb, nf 4-11 -> KVb
            bf16x8 a0 = *(const bf16x8*)&XN[fr][fk * 8];
            bf16x8 a1 = *(const bf16x8*)&XN[fr][fk * 8 + 32];
#pragma unroll
            for (int nf = 0; nf < 12; ++nf) {
                const short* bp = lq + (nf * 16 + fr) * 64 + fk * 8;
                bf16x8 bv0 = *(const bf16x8*)bp;
                bf16x8 bv1 = *(const bf16x8*)(bp + 32);
                f32x4 acc = {};
                acc = __builtin_amdgcn_mfma_f32_16x16x32_bf16(a0, bv0, acc, 0, 0, 0);
                acc = __builtin_amdgcn_mfma_f32_16x16x32_bf16(a1, bv1, acc, 0, 0, 0);
                int cc = nf * 16 + fr;
#pragma unroll
                for (int rr = 0; rr < 4; ++rr) {
                    if (nf < 4) Qb[rb + rr][cc] = f2bf_s(acc[rr]);
                    else        KVb[rb + rr][cc - 64] = f2bf_s(acc[rr]);
                }
            }
        }
        __syncthreads();

        {   // attention: lane = (s=lane>>3, h=(lane>>1)&3, qi=lane&1); 2 keys, registers
            int s_ = lane >> 3, h = (lane >> 1) & 3, qi = lane & 1;
            int qrow = s_ * 2 + qi;
            float q[16];
            {
                const unsigned* qp = (const unsigned*)&Qb[qrow][h * 16];
#pragma unroll
                for (int e = 0; e < 8; ++e) { q[2 * e] = bf_lo(qp[e]); q[2 * e + 1] = bf_hi(qp[e]); }
            }
            float sc[2];
#pragma unroll
            for (int j = 0; j < 2; ++j) {
                const unsigned* kp = (const unsigned*)&KVb[s_ * 2 + j][h * 16];
                float a = 0.f;
#pragma unroll
                for (int e = 0; e < 8; ++e)
                    a += q[2 * e] * bf_lo(kp[e]) + q[2 * e + 1] * bf_hi(kp[e]);
                a = a * 0.25f + prevM[j];
                prevM[j] = a;
                sc[j] = a;
            }
            float mx = fmaxf(sc[0], sc[1]);
            float e0 = expf(sc[0] - mx), e1 = expf(sc[1] - mx);
            float inv = 1.f / (e0 + e1);
            float p0 = e0 * inv, p1 = e1 * inv;
            const unsigned* v0 = (const unsigned*)&KVb[s_ * 2 + 0][64 + h * 16];
            const unsigned* v1 = (const unsigned*)&KVb[s_ * 2 + 1][64 + h * 16];
            unsigned* op = (unsigned*)&XN[qrow][h * 16];
#pragma unroll
            for (int e = 0; e < 8; ++e) {
                unsigned ua = v0[e], ub = v1[e];
                float olo = p0 * bf_lo(ua) + p1 * bf_lo(ub);
                float ohi = p0 * bf_hi(ua) + p1 * bf_hi(ub);
                op[e] = packbf(olo, ohi);
            }
        }
        __syncthreads();

        {   // out proj + residual
            bf16x8 a0 = *(const bf16x8*)&XN[fr][fk * 8];
            bf16x8 a1 = *(const bf16x8*)&XN[fr][fk * 8 + 32];
#pragma unroll
            for (int nf = 0; nf < 4; ++nf) {
                const short* bp = lo + (nf * 16 + fr) * 64 + fk * 8;
                bf16x8 bv0 = *(const bf16x8*)bp;
                bf16x8 bv1 = *(const bf16x8*)(bp + 32);
                f32x4 acc = {};
                acc = __builtin_amdgcn_mfma_f32_16x16x32_bf16(a0, bv0, acc, 0, 0, 0);
                acc = __builtin_amdgcn_mfma_f32_16x16x32_bf16(a1, bv1, acc, 0, 0, 0);
                int cc = nf * 16 + fr;
#pragma unroll
                for (int rr = 0; rr < 4; ++rr) Xr[rb + rr][cc] += acc[rr];
            }
        }
        __syncthreads();

        {   // LN2 -> XN (register-blocked)
            int r = lane >> 2, c = (lane & 3) * 16;
            float4 va[4];
#pragma unroll
            for (int u = 0; u < 4; ++u) va[u] = *(const float4*)&Xr[r][c + u * 4];
            float s = 0.f, s2 = 0.f;
#pragma unroll
            for (int u = 0; u < 4; ++u) {
                s  += va[u].x + va[u].y + va[u].z + va[u].w;
                s2 += va[u].x * va[u].x + va[u].y * va[u].y + va[u].z * va[u].z + va[u].w * va[u].w;
            }
            s  += __shfl_xor(s, 1, 64);  s2 += __shfl_xor(s2, 1, 64);
            s  += __shfl_xor(s, 2, 64);  s2 += __shfl_xor(s2, 2, 64);
            float m = s * (1.f / 64.f);
            float var = s2 * (1.f / 64.f) - m * m;
            float rstd = rsqrtf(var + EPSV);
            unsigned pk[8];
#pragma unroll
            for (int u = 0; u < 4; ++u) {
                float4 wv4 = *(const float4*)(l2w + c + u * 4);
                float4 bv4 = *(const float4*)(l2b + c + u * 4);
                pk[2 * u]     = packbf((va[u].x - m) * rstd * wv4.x + bv4.x,
                                       (va[u].y - m) * rstd * wv4.y + bv4.y);
                pk[2 * u + 1] = packbf((va[u].z - m) * rstd * wv4.z + bv4.z,
                                       (va[u].w - m) * rstd * wv4.w + bv4.w);
            }
            *(uint4*)&XN[r][c]     = *(uint4*)&pk[0];
            *(uint4*)&XN[r][c + 8] = *(uint4*)&pk[4];
        }
        __syncthreads();

        {   // FFN: ff1 halves -> KVb, ff2 acc in regs
            bf16x8 a0 = *(const bf16x8*)&XN[fr][fk * 8];
            bf16x8 a1 = *(const bf16x8*)&XN[fr][fk * 8 + 32];
            f32x4 facc[4] = {};
#pragma unroll
            for (int half = 0; half < 2; ++half) {
#pragma unroll
                for (int nf = 0; nf < 8; ++nf) {
                    int ng = half * 128 + nf * 16;
                    const short* bp = lf1 + (ng + fr) * 64 + fk * 8;
                    bf16x8 bv0 = *(const bf16x8*)bp;
                    bf16x8 bv1 = *(const bf16x8*)(bp + 32);
                    f32x4 acc = {};
                    acc = __builtin_amdgcn_mfma_f32_16x16x32_bf16(a0, bv0, acc, 0, 0, 0);
                    acc = __builtin_amdgcn_mfma_f32_16x16x32_bf16(a1, bv1, acc, 0, 0, 0);
                    int cc = nf * 16 + fr;
                    float bias1 = fb1[ng + fr];
#pragma unroll
                    for (int rr = 0; rr < 4; ++rr)
                        KVb[rb + rr][cc] = f2bf_s(gelu_f(acc[rr] + bias1));
                }
                __syncthreads();
                bf16x8 fa[4];
#pragma unroll
                for (int kf = 0; kf < 4; ++kf)
                    fa[kf] = *(const bf16x8*)&KVb[fr][kf * 32 + fk * 8];
#pragma unroll
                for (int nf = 0; nf < 4; ++nf) {
                    const short* bp = lf2 + (nf * 16 + fr) * 256 + half * 128 + fk * 8;
#pragma unroll
                    for (int kf = 0; kf < 4; ++kf)
                        facc[nf] = __builtin_amdgcn_mfma_f32_16x16x32_bf16(
                            fa[kf], *(const bf16x8*)(bp + kf * 32), facc[nf], 0, 0, 0);
                }
                __syncthreads();
            }
#pragma unroll
            for (int nf = 0; nf < 4; ++nf) {
                int cc = nf * 16 + fr;
                float bias2 = fb2[cc];
#pragma unroll
                for (int rr = 0; rr < 4; ++rr) Xr[rb + rr][cc] += facc[nf][rr] + bias2;
            }
        }
        __syncthreads();
    }

    {   // store back
        int r = lane >> 2, c0 = (lane & 3) * 16;
        float* gx = xflat + (size_t)(b0 + (r >> 1)) * FLATN + (r & 1) * 64 + c0;
#pragma unroll
        for (int u = 0; u < 4; ++u) *(float4*)(gx + u * 4) = *(const float4*)&Xr[r][c0 + u * 4];
    }
}

// ---------------- macro encoder (MFMA attn): TWO samples / block, FOUR waves ----------------
// r16: r14's proven 4-wave structure, s2 in {0,1} loop per phase (rows s2*16+..).
// Barrier count per block unchanged -> barrier overhead per sample HALVES.
// LDS 27.6KB -> 5 blocks/CU.
__global__ __launch_bounds__(256) void macro_enc_mfma(
    float* __restrict__ xflat, __hip_bfloat16* __restrict__ Abf,
    const short* __restrict__ wT,
    const float* __restrict__ ln1w, const float* __restrict__ ln1b,
    const float* __restrict__ ln2w, const float* __restrict__ ln2b,
    const float* __restrict__ b1, const float* __restrict__ b2)
{
    __shared__ __align__(16) float Xr[32][68];
    __shared__ __align__(16) short XN[32][72];
    __shared__ __align__(16) short Qb[32][72];
    __shared__ __align__(16) short Kb[32][72];
    __shared__ __align__(16) short VT[32][72];   // VT[s2*16+d][h*16 + token]

    int tid = threadIdx.x;
    int lane = tid & 63, w = tid >> 6;
    int b0 = blockIdx.x * 2;

    {   // load residual: 256 threads x 8 floats (32 rows)
        int r = tid >> 3, c0 = (tid & 7) * 8;
        const float* gx = xflat + (size_t)(b0 + (r >> 4)) * FLATN + (r & 15) * 64 + c0;
        *(float4*)&Xr[r][c0]     = *(const float4*)gx;
        *(float4*)&Xr[r][c0 + 4] = *(const float4*)(gx + 4);
    }
    __syncthreads();

    int fr = lane & 15, fk = lane >> 4;
    int rb = 4 * fk;
    f32x4 prevA[2] = {};   // per sample; this wave's head: h = w

    for (int p = 0; p < 2; ++p) {
        const short* lq  = wT + p * 49152;
        const short* lo  = lq + 12288;
        const short* lf1 = lo + 4096;
        const short* lf2 = lf1 + 16384;
        const float* l1w = ln1w + p * 64; const float* l1b = ln1b + p * 64;
        const float* l2w = ln2w + p * 64; const float* l2b = ln2b + p * 64;
        const float* fb1 = b1 + p * 256;  const float* fb2 = b2 + p * 64;

        {   // LN1 -> XN (register-blocked), both samples
#pragma unroll
            for (int s2i = 0; s2i < 2; ++s2i) {
                int r = s2i * 16 + w * 4 + (lane >> 4);
                int c = (lane & 15) * 4;
                float4 v = *(const float4*)&Xr[r][c];
                float s  = v.x + v.y + v.z + v.w;
                float s2 = v.x * v.x + v.y * v.y + v.z * v.z + v.w * v.w;
#pragma unroll
                for (int o = 1; o < 16; o <<= 1) {
                    s  += __shfl_xor(s, o, 64);
                    s2 += __shfl_xor(s2, o, 64);
                }
                float m = s * (1.f / 64.f);
                float var = s2 * (1.f / 64.f) - m * m;
                float rstd = rsqrtf(var + EPSV);
                float4 wv4 = *(const float4*)(l1w + c);
                float4 bv4 = *(const float4*)(l1b + c);
                unsigned pk0 = packbf((v.x - m) * rstd * wv4.x + bv4.x,
                                      (v.y - m) * rstd * wv4.y + bv4.y);
                unsigned pk1 = packbf((v.z - m) * rstd * wv4.z + bv4.z,
                                      (v.w - m) * rstd * wv4.w + bv4.w);
                unsigned long long pk = (unsigned long long)pk0 | ((unsigned long long)pk1 << 32);
                *(unsigned long long*)&XN[r][c] = pk;
            }
        }
        __syncthreads();

        {   // qkv MFMA: wave w does nf = w*3 .. w*3+2, both samples
#pragma unroll
            for (int s2i = 0; s2i < 2; ++s2i) {
                int ro = s2i * 16;
                bf16x8 a0 = *(const bf16x8*)&XN[ro + fr][fk * 8];
                bf16x8 a1 = *(const bf16x8*)&XN[ro + fr][fk * 8 + 32];
#pragma unroll
                for (int nn = 0; nn < 3; ++nn) {
                    int nf = w * 3 + nn;
                    const short* bp = lq + (nf * 16 + fr) * 64 + fk * 8;
                    bf16x8 bv0 = *(const bf16x8*)bp;
                    bf16x8 bv1 = *(const bf16x8*)(bp + 32);
                    f32x4 acc = {};
                    acc = __builtin_amdgcn_mfma_f32_16x16x32_bf16(a0, bv0, acc, 0, 0, 0);
                    acc = __builtin_amdgcn_mfma_f32_16x16x32_bf16(a1, bv1, acc, 0, 0, 0);
                    if (nf < 8) {
#pragma unroll
                        for (int rr = 0; rr < 4; ++rr) {
                            short sv = f2bf_s(acc[rr]);
                            if (nf < 4) Qb[ro + rb + rr][nf * 16 + fr] = sv;
                            else        Kb[ro + rb + rr][(nf - 4) * 16 + fr] = sv;
                        }
                    } else {
                        unsigned long long pkv =
                            (unsigned long long)packbf(acc[0], acc[1]) |
                            ((unsigned long long)packbf(acc[2], acc[3]) << 32);
                        *(unsigned long long*)&VT[ro + fr][(nf - 8) * 16 + rb] = pkv;
                    }
                }
            }
        }
        __syncthreads();

        {   // MFMA attention: wave w handles head h = w, both samples
            bf16x8 zero8 = {};
            int h = w;
#pragma unroll
            for (int s2i = 0; s2i < 2; ++s2i) {
                int ro = s2i * 16;
                bf16x8 ka = zero8, qa = zero8, va = zero8;
                if (fk < 2) {
                    ka = *(const bf16x8*)&Kb[ro + fr][h * 16 + fk * 8];
                    qa = *(const bf16x8*)&Qb[ro + fr][h * 16 + fk * 8];
                    va = *(const bf16x8*)&VT[ro + fr][h * 16 + fk * 8];
                }
                f32x4 s = {};
                s = __builtin_amdgcn_mfma_f32_16x16x32_bf16(ka, qa, s, 0, 0, 0);
#pragma unroll
                for (int rr = 0; rr < 4; ++rr) {
                    s[rr] = s[rr] * 0.25f + prevA[s2i][rr];
                    prevA[s2i][rr] = s[rr];
                }
                float m = fmaxf(fmaxf(s[0], s[1]), fmaxf(s[2], s[3]));
                m = fmaxf(m, __shfl_xor(m, 16, 64));
                m = fmaxf(m, __shfl_xor(m, 32, 64));
                float e0 = expf(s[0] - m), e1 = expf(s[1] - m);
                float e2 = expf(s[2] - m), e3 = expf(s[3] - m);
                float sum = e0 + e1 + e2 + e3;
                sum += __shfl_xor(sum, 16, 64);
                sum += __shfl_xor(sum, 32, 64);
                float inv = 1.f / sum;
                int pk0 = (int)packbf(e0 * inv, e1 * inv);
                int pk1 = (int)packbf(e2 * inv, e3 * inv);
                int s1 = fr + (((2 * fk) & 3) << 4);
                int s2 = fr + (((2 * fk + 1) & 3) << 4);
                int d0 = __shfl(pk0, s1, 64), d1 = __shfl(pk1, s1, 64);
                int d2 = __shfl(pk0, s2, 64), d3 = __shfl(pk1, s2, 64);
                bf16x8 pa = zero8;
                if (fk < 2) {
                    union { int i[4]; bf16x8 v; } u;
                    u.i[0] = d0; u.i[1] = d1; u.i[2] = d2; u.i[3] = d3;
                    pa = u.v;
                }
                f32x4 o = {};
                o = __builtin_amdgcn_mfma_f32_16x16x32_bf16(pa, va, o, 0, 0, 0);
#pragma unroll
                for (int rr = 0; rr < 4; ++rr)
                    XN[ro + 4 * fk + rr][h * 16 + fr] = f2bf_s(o[rr]);
            }
        }
        __syncthreads();

        {   // out proj + residual: wave w does nf = w, both samples
            int nf = w;
            const short* bp = lo + (nf * 16 + fr) * 64 + fk * 8;
            bf16x8 bv0 = *(const bf16x8*)bp;
            bf16x8 bv1 = *(const bf16x8*)(bp + 32);
#pragma unroll
            for (int s2i = 0; s2i < 2; ++s2i) {
                int ro = s2i * 16;
                bf16x8 a0 = *(const bf16x8*)&XN[ro + fr][fk * 8];
                bf16x8 a1 = *(const bf16x8*)&XN[ro + fr][fk * 8 + 32];
                f32x4 acc = {};
                acc = __builtin_amdgcn_mfma_f32_16x16x32_bf16(a0, bv0, acc, 0, 0, 0);
                acc = __builtin_amdgcn_mfma_f32_16x16x32_bf16(a1, bv1, acc, 0, 0, 0);
                int cc = nf * 16 + fr;
#pragma unroll
                for (int rr = 0; rr < 4; ++rr) Xr[ro + rb + rr][cc] += acc[rr];
            }
        }
        __syncthreads();

        {   // LN2 -> XN (register-blocked), both samples
#pragma unroll
            for (int s2i = 0; s2i < 2; ++s2i) {
                int r = s2i * 16 + w * 4 + (lane >> 4);
                int c = (lane & 15) * 4;
                float4 v = *(const float4*)&Xr[r][c];
                float s  = v.x + v.y + v.z + v.w;
                float s2 = v.x * v.x + v.y * v.y + v.z * v.z + v.w * v.w;
#pragma unroll
                for (int o = 1; o < 16; o <<= 1) {
                    s  += __shfl_xor(s, o, 64);
                    s2 += __shfl_xor(s2, o, 64);
                }
                float m = s * (1.f / 64.f);
                float var = s2 * (1.f / 64.f) - m * m;
                float rstd = rsqrtf(var + EPSV);
                float4 wv4 = *(const float4*)(l2w + c);
                float4 bv4 = *(const float4*)(l2b + c);
                unsigned pk0 = packbf((v.x - m) * rstd * wv4.x + bv4.x,
                                      (v.y - m) * rstd * wv4.y + bv4.y);
                unsigned pk1 = packbf((v.z - m) * rstd * wv4.z + bv4.z,
                                      (v.w - m) * rstd * wv4.w + bv4.w);
                unsigned long long pk = (unsigned long long)pk0 | ((unsigned long long)pk1 << 32);
                *(unsigned long long*)&XN[r][c] = pk;
            }
        }
        __syncthreads();

        {   // FFN: ff1 wave w nf = w*2..w*2+1 (nf 0-3 ->Qb, 4-7 ->Kb); ff2 nf = w; both samples
            f32x4 facc[2] = {};
#pragma unroll
            for (int half = 0; half < 2; ++half) {
#pragma unroll
                for (int s2i = 0; s2i < 2; ++s2i) {
                    int ro = s2i * 16;
                    bf16x8 a0 = *(const bf16x8*)&XN[ro + fr][fk * 8];
                    bf16x8 a1 = *(const bf16x8*)&XN[ro + fr][fk * 8 + 32];
#pragma unroll
                    for (int nn = 0; nn < 2; ++nn) {
                        int nf = w * 2 + nn;
                        int ng = half * 128 + nf * 16;
                        const short* bp = lf1 + (ng + fr) * 64 + fk * 8;
                        bf16x8 bv0 = *(const bf16x8*)bp;
                        bf16x8 bv1 = *(const bf16x8*)(bp + 32);
                        f32x4 acc = {};
                        acc = __builtin_amdgcn_mfma_f32_16x16x32_bf16(a0, bv0, acc, 0, 0, 0);
                        acc = __builtin_amdgcn_mfma_f32_16x16x32_bf16(a1, bv1, acc, 0, 0, 0);
                        int cc = nf * 16 + fr;
                        float bias1 = fb1[ng + fr];
#pragma unroll
                        for (int rr = 0; rr < 4; ++rr) {
                            short sv = f2bf_s(gelu_f(acc[rr] + bias1));
                            if (cc < 64) Qb[ro + rb + rr][cc] = sv;
                            else         Kb[ro + rb + rr][cc - 64] = sv;
                        }
                    }
                }
                __syncthreads();
#pragma unroll
                for (int s2i = 0; s2i < 2; ++s2i) {
                    int ro = s2i * 16;
                    bf16x8 fa[4];
                    fa[0] = *(const bf16x8*)&Qb[ro + fr][fk * 8];
                    fa[1] = *(const bf16x8*)&Qb[ro + fr][32 + fk * 8];
                    fa[2] = *(const bf16x8*)&Kb[ro + fr][fk * 8];
                    fa[3] = *(const bf16x8*)&Kb[ro + fr][32 + fk * 8];
                    int nf = w;
                    const short* bp = lf2 + (nf * 16 + fr) * 256 + half * 128 + fk * 8;
#pragma unroll
                    for (int kf = 0; kf < 4; ++kf)
                        facc[s2i] = __builtin_amdgcn_mfma_f32_16x16x32_bf16(
                            fa[kf], *(const bf16x8*)(bp + kf * 32), facc[s2i], 0, 0, 0);
                }
                __syncthreads();
            }
            {
                int cc = w * 16 + fr;
                float bias2 = fb2[cc];
#pragma unroll
                for (int s2i = 0; s2i < 2; ++s2i)
#pragma unroll
                    for (int rr = 0; rr < 4; ++rr)
                        Xr[s2i * 16 + rb + rr][cc] += facc[s2i][rr] + bias2;
            }
        }
        __syncthreads();
    }

    // store residual (fp32) + bf16 token part of Abf (both samples)
    {
        int r = tid >> 3, c0 = (tid & 7) * 8;
        int b = b0 + (r >> 4);
        float* gx = xflat + (size_t)b * FLATN + (r & 15) * 64 + c0;
        *(float4*)gx       = *(const float4*)&Xr[r][c0];
        *(float4*)(gx + 4) = *(const float4*)&Xr[r][c0 + 4];
        unsigned int pk[4];
#pragma unroll
        for (int e = 0; e < 4; ++e) pk[e] = packbf(Xr[r][c0 + 2 * e], Xr[r][c0 + 2 * e + 1]);
        unsigned int* ga = (unsigned int*)(Abf + (size_t)b * KP1 + (r & 15) * 64 + c0);
#pragma unroll
        for (int e = 0; e < 4; ++e) ga[e] = pk[e];
    }
    if (tid < 128) {
        int s2i = tid >> 6, c = tid & 63;
        int b = b0 + s2i;
        float v = (c < CONTN) ? xflat[(size_t)b * FLATN + 1024 + c] : 0.f;
        Abf[(size_t)b * KP1 + 1024 + c] = __float2bfloat16(v);
    }
}

// ---------------- transpose + convert: W[K][N] fp32 -> Wt[Np][Kp] bf16 (zero-padded) ----
__global__ __launch_bounds__(256) void transpose_conv(
    const float* __restrict__ src, __hip_bfloat16* __restrict__ dst,
    int K, int N, int Kp, int Np)
{
    __shared__ float T[32][33];
    int k0 = blockIdx.y * 32, n0 = blockIdx.x * 32;
    int tn = threadIdx.x & 31, tk = threadIdx.x >> 5;
#pragma unroll
    for (int r = 0; r < 4; ++r) {
        int k = k0 + tk + r * 8, n = n0 + tn;
        T[tk + r * 8][tn] = (k < K && n < N) ? src[(size_t)k * N + n] : 0.f;
    }
    __syncthreads();
#pragma unroll
    for (int r = 0; r < 4; ++r) {
        int n = n0 + tk + r * 8, k = k0 + tn;
        dst[(size_t)n * Kp + k] = __float2bfloat16(T[tn][tk + r * 8]);
    }
}

// ---------------- bf16 MFMA GEMM: m97 structure (single 32KB buffer, 2 barriers/K-step)
// + T2 both-sides swizzle (conflict-free). 3 blocks/CU (launch_bounds 3 waves/SIMD).
// MODE 1: C[M][Np] bf16 gelu via slot-swizzled LDS restage (coalesced 128B stores).
// MODE 2: partials[row][bx] = sum_cols gelu(.)*w3[col] (fused final dot).
template <int MODE>
__global__ __launch_bounds__(256, 3) void gemm_mfma(
    const __hip_bfloat16* __restrict__ A, const __hip_bfloat16* __restrict__ Bt,
    const float* __restrict__ bias, int bias_n,
    __hip_bfloat16* __restrict__ Cbf, const float* __restrict__ w3,
    float* __restrict__ partials, int Np, int Kp)
{
    __shared__ __align__(16) short LDSbuf[16384];   // 32KB: A 8192 | B 8192 shorts

    int tid = threadIdx.x;
    int lane = tid & 63, wave = tid >> 6;

    // bijective XCD swizzle (m204)
    int nbx = gridDim.x;
    int nwg = nbx * gridDim.y;
    int wgid = blockIdx.y * nbx + blockIdx.x;
    int q = nwg >> 3, r = nwg & 7;
    int xcd = wgid & 7, loc = wgid >> 3;
    int sw = (xcd < r ? xcd * (q + 1) : r * (q + 1) + (xcd - r) * q) + loc;
    int bm = (sw / nbx) * 128, bx = sw % nbx, bn = bx * 128;

    // staging addresses: lane l -> row (l>>3), k-slot (l&7)^(l>>3)  [T2 pre-swizzle]
    int lrow8 = lane >> 3;
    int lk8sw = ((lane & 7) ^ lrow8) * 8;
    const __hip_bfloat16* Ag = A  + (size_t)(bm + wave * 32 + lrow8) * Kp + lk8sw;
    const __hip_bfloat16* Bg = Bt + (size_t)(bn + wave * 32 + lrow8) * Kp + lk8sw;
    short* Al = LDSbuf + wave * 32 * 64;
    short* Bl = Al + 8192;

    int wm = (wave >> 1) * 64, wn = (wave & 1) * 64;
    int lrow = lane & 15, lk = lane >> 4;
    int key = lane & 7;                     // = (row&7) for this lane's fragment rows

    f32x4 acc[4][4] = {};
    int nt = Kp >> 6;

    for (int t = 0; t < nt; ++t) {
        int k0 = t << 6;
        __syncthreads();                    // prev tile's reads complete
#pragma unroll
        for (int it = 0; it < 4; ++it) {
            gload16(Ag + (size_t)(it * 8) * Kp + k0, Al + it * 8 * 64);
            gload16(Bg + (size_t)(it * 8) * Kp + k0, Bl + it * 8 * 64);
        }
        __syncthreads();                    // vmcnt(0) drain -> tile ready
#pragma unroll
        for (int ks = 0; ks < 2; ++ks) {
            int so = ((ks * 4 + lk) ^ key) * 8;     // swizzled slot offset (shorts)
            bf16x8 af[4], bf[4];
#pragma unroll
            for (int i = 0; i < 4; ++i) af[i] = *(const bf16x8*)(LDSbuf + (wm + i * 16 + lrow) * 64 + so);
#pragma unroll
            for (int j = 0; j < 4; ++j) bf[j] = *(const bf16x8*)(LDSbuf + 8192 + (wn + j * 16 + lrow) * 64 + so);
#pragma unroll
            for (int i = 0; i < 4; ++i)
#pragma unroll
                for (int j = 0; j < 4; ++j)
                    acc[i][j] = __builtin_amdgcn_mfma_f32_16x16x32_bf16(af[i], bf[j], acc[i][j], 0, 0, 0);
        }
    }
    __syncthreads();   // all LDS reads done; buffer reusable for epilogue

    if (MODE == 1) {
        // slot-swizzled LDS restage -> full-line coalesced bf16 stores
        short* Cs = LDSbuf;                 // [128][128] shorts = 32KB
#pragma unroll
        for (int j = 0; j < 4; ++j) {
            int cl = wn + j * 16 + lrow;
            float bv = (bn + cl < bias_n) ? bias[bn + cl] : 0.f;
#pragma unroll
            for (int i = 0; i < 4; ++i) {
#pragma unroll
                for (int rr = 0; rr < 4; ++rr) {
                    int rl = wm + i * 16 + 4 * lk + rr;
                    int pos = ((((cl >> 3) ^ (rl & 7)) << 3) | (cl & 7));
                    Cs[rl * 128 + pos] = f2bf_s(gelu_f(acc[i][j][rr] + bv));
                }
            }
        }
        __syncthreads();
        int rloc = tid >> 1, half = tid & 1;
        int4* dst = (int4*)(Cbf + (size_t)(bm + rloc) * Np + bn + half * 64);
#pragma unroll
        for (int u = 0; u < 8; ++u) {
            int slot = half * 8 + (u ^ (rloc & 7));
            dst[u] = *(const int4*)&Cs[rloc * 128 + slot * 8];
        }
    } else {
        // fused w3 reduction
        float rs[16];
#pragma unroll
        for (int t = 0; t < 16; ++t) rs[t] = 0.f;
#pragma unroll
        for (int j = 0; j < 4; ++j) {
            int gcol = bn + wn + j * 16 + lrow;
            float bv  = (gcol < bias_n) ? bias[gcol] : 0.f;
            float w3v = (gcol < H2N) ? w3[gcol] : 0.f;
#pragma unroll
            for (int i = 0; i < 4; ++i)
#pragma unroll
                for (int rr = 0; rr < 4; ++rr)
                    rs[i * 4 + rr] += gelu_f(acc[i][j][rr] + bv) * w3v;
        }
#pragma unroll
        for (int o = 1; o < 16; o <<= 1)
#pragma unroll
            for (int t = 0; t < 16; ++t) rs[t] += __shfl_xor(rs[t], o, 64);
        float* pr = (float*)LDSbuf;         // [128][2]
        if (lrow == 0) {
#pragma unroll
            for (int i = 0; i < 4; ++i)
#pragma unroll
                for (int rr = 0; rr < 4; ++rr)
                    pr[(wm + i * 16 + 4 * lk + rr) * 2 + (wave & 1)] = rs[i * 4 + rr];
        }
        __syncthreads();
        if (tid < 128)
            partials[(size_t)(bm + tid) * nbx + bx] = pr[tid * 2] + pr[tid * 2 + 1];
    }
}

// ---------------- logits = b3 + sum over N-tiles of partials ----------------
__global__ __launch_bounds__(256) void reduce_partials(
    const float* __restrict__ partials, const float* __restrict__ b3,
    float* __restrict__ out, int n, int nbx)
{
    int b = blockIdx.x * 256 + threadIdx.x;
    if (b >= n) return;
    float s = b3[0];
    for (int x = 0; x < nbx; ++x) s += partials[(size_t)b * nbx + x];
    out[b] = s;
}

extern "C" void kernel_launch(void* const* d_in, const int* in_sizes, int n_in,
                              void* d_out, int out_size, void* d_ws, size_t ws_size,
                              hipStream_t stream)
{
    const int*   x_cat      = (const int*)  d_in[0];
    const float* x_cont     = (const float*)d_in[1];
    const float* shared_emb = (const float*)d_in[2];
    const float* emb        = (const float*)d_in[3];
    const float* mi_qkv  = (const float*)d_in[4];
    const float* mi_out  = (const float*)d_in[5];
    const float* mi_ln1w = (const float*)d_in[6];
    const float* mi_ln1b = (const float*)d_in[7];
    const float* mi_ln2w = (const float*)d_in[8];
    const float* mi_ln2b = (const float*)d_in[9];
    const float* mi_w1   = (const float*)d_in[10];
    const float* mi_b1   = (const float*)d_in[11];
    const float* mi_w2   = (const float*)d_in[12];
    const float* mi_b2   = (const float*)d_in[13];
    const float* ma_qkv  = (const float*)d_in[14];
    const float* ma_out  = (const float*)d_in[15];
    const float* ma_ln1w = (const float*)d_in[16];
    const float* ma_ln1b = (const float*)d_in[17];
    const float* ma_ln2w = (const float*)d_in[18];
    const float* ma_ln2b = (const float*)d_in[19];
    const float* ma_w1   = (const float*)d_in[20];
    const float* ma_b1   = (const float*)d_in[21];
    const float* ma_w2   = (const float*)d_in[22];
    const float* ma_b2   = (const float*)d_in[23];
    const float* cont_w  = (const float*)d_in[24];
    const float* cont_b  = (const float*)d_in[25];
    const float* w1      = (const float*)d_in[26];
    const float* b1      = (const float*)d_in[27];
    const float* w2      = (const float*)d_in[28];
    const float* b2      = (const float*)d_in[29];
    const float* w3      = (const float*)d_in[30];
    const float* b3      = (const float*)d_in[31];
    float* out = (float*)d_out;

    const int NBX2 = NP2 / 128;          // 17 N-tiles in GEMM2
    const size_t ENC_SH = 4 * 49152;     // ma L0, ma L1, mi L0, mi L1
    const size_t FIXED = ((size_t)NP1 * KP1 + (size_t)NP2 * KP2 + ENC_SH) * 2;
    const size_t PER_ROW = (size_t)NP1 * 2 + (size_t)FLATN * 4 + (size_t)KP1 * 2 + (size_t)NBX2 * 4;
    size_t avail = (ws_size > FIXED) ? ws_size - FIXED : 0;
    long long chl = (long long)(avail / PER_ROW);
    int CH = (int)((chl / 128) * 128);
    if (CH > BATCH) CH = BATCH;
    if (CH < 128) CH = 128;

    char* p = (char*)d_ws;
    __hip_bfloat16* w1T = (__hip_bfloat16*)p; p += (size_t)NP1 * KP1 * 2;
    __hip_bfloat16* w2T = (__hip_bfloat16*)p; p += (size_t)NP2 * KP2 * 2;
    __hip_bfloat16* encT = (__hip_bfloat16*)p; p += ENC_SH * 2;
    __hip_bfloat16* h1  = (__hip_bfloat16*)p; p += (size_t)CH * NP1 * 2;
    float* xflat = (float*)p;                 p += (size_t)CH * FLATN * 4;
    __hip_bfloat16* Abf = (__hip_bfloat16*)p; p += (size_t)CH * KP1 * 2;
    float* partials = (float*)p;

    transpose_conv<<<dim3(NP1 / 32, KP1 / 32), 256, 0, stream>>>(w1, w1T, FLATN, H1N, KP1, NP1);
    transpose_conv<<<dim3(NP2 / 32, KP2 / 32), 256, 0, stream>>>(w2, w2T, H1N, H2N, KP2, NP2);

    // encoder weights -> bf16 [N][K] per layer: qkvT | outT | ff1T | ff2T
    const float* enc_qkv[2] = {ma_qkv, mi_qkv};
    const float* enc_out[2] = {ma_out, mi_out};
    const float* enc_w1[2]  = {ma_w1,  mi_w1};
    const float* enc_w2[2]  = {ma_w2,  mi_w2};
    for (int grp = 0; grp < 2; ++grp) {
        for (int pl = 0; pl < 2; ++pl) {
            __hip_bfloat16* base = encT + (size_t)(grp * 2 + pl) * 49152;
            transpose_conv<<<dim3(192 / 32, 64 / 32), 256, 0, stream>>>(
                enc_qkv[grp] + pl * 64 * 192, base, 64, 192, 64, 192);
            transpose_conv<<<dim3(64 / 32, 64 / 32), 256, 0, stream>>>(
                enc_out[grp] + pl * 64 * 64, base + 12288, 64, 64, 64, 64);
            transpose_conv<<<dim3(256 / 32, 64 / 32), 256, 0, stream>>>(
                enc_w1[grp] + pl * 64 * 256, base + 16384, 64, 256, 64, 256);
            transpose_conv<<<dim3(64 / 32, 256 / 32), 256, 0, stream>>>(
                enc_w2[grp] + pl * 256 * 64, base + 32768, 256, 64, 256, 64);
        }
    }

    for (int m0 = 0; m0 < BATCH; m0 += CH) {
        int mc = BATCH - m0 < CH ? BATCH - m0 : CH;   // multiple of 128

        build_tokens<<<(mc * 1024) / 256, 256, 0, stream>>>(
            x_cat + (size_t)m0 * NCATS, shared_emb, emb, xflat);
        cont_proj<<<(mc * 16) / 256, 256, 0, stream>>>(
            x_cont + (size_t)m0 * CONTN, cont_w, cont_b, xflat);
        micro_enc_mfma<<<mc / 8, 64, 0, stream>>>(
            xflat, (const short*)encT + 2 * 49152, mi_ln1w, mi_ln1b, mi_ln2w, mi_ln2b, mi_b1, mi_b2);
        macro_enc_mfma<<<mc / 2, 256, 0, stream>>>(
            xflat, Abf, (const short*)encT, ma_ln1w, ma_ln1b, ma_ln2w, ma_ln2b, ma_b1, ma_b2);

        gemm_mfma<1><<<dim3(NP1 / 128, mc / 128), 256, 0, stream>>>(
            Abf, w1T, b1, H1N, h1, nullptr, nullptr, NP1, KP1);
        gemm_mfma<2><<<dim3(NBX2, mc / 128), 256, 0, stream>>>(
            h1, w2T, b2, H2N, nullptr, w3, partials, NP2, KP2);

        reduce_partials<<<(mc + 255) / 256, 256, 0, stream>>>(partials, b3, out + m0, mc, NBX2);
    }
}

// Round 17
// 1135.110 us; speedup vs baseline: 1.1626x; 1.0838x over previous
//
#include <hip/hip_runtime.h>
#include <hip/hip_bf16.h>
#include <math.h>

#define BATCH  16384
#define NCATS  16
#define VOCABN 1000
#define DIMD   64
#define SHARED_E 10
#define INDIVE 54
#define CONTN  16
#define FLATN  1040   // NCATS*DIMD + CONTN
#define H1N    4160
#define H2N    2080
#define KP1    1088   // FLATN padded to mult of 64
#define NP1    4224   // H1N padded to mult of 128
#define KP2    4224   // = NP1 (GEMM2 K)
#define NP2    2176   // H2N padded to mult of 128
#define EPSV   1e-5f

typedef __attribute__((ext_vector_type(8))) short bf16x8;
typedef __attribute__((ext_vector_type(4))) float f32x4;

__device__ __forceinline__ float gelu_f(float x) {
    return 0.5f * x * (1.0f + erff(x * 0.70710678118654752440f));
}
__device__ __forceinline__ float wsum(float v) {
#pragma unroll
    for (int o = 32; o > 0; o >>= 1) v += __shfl_xor(v, o, 64);
    return v;
}
__device__ __forceinline__ short f2bf_s(float a) {
    __hip_bfloat16 x = __float2bfloat16(a);
    return *reinterpret_cast<short*>(&x);
}
__device__ __forceinline__ unsigned int packbf(float a, float b) {
    __hip_bfloat16 x = __float2bfloat16(a), y = __float2bfloat16(b);
    unsigned short ux = *reinterpret_cast<unsigned short*>(&x);
    unsigned short uy = *reinterpret_cast<unsigned short*>(&y);
    return (unsigned)ux | ((unsigned)uy << 16);
}
__device__ __forceinline__ float bf_lo(unsigned int u) { return __uint_as_float(u << 16); }
__device__ __forceinline__ float bf_hi(unsigned int u) { return __uint_as_float(u & 0xffff0000u); }
// async global->LDS, 16B per lane; LDS dest is wave-uniform base + lane*16 (m97)
__device__ __forceinline__ void gload16(const void* g, void* l) {
    __builtin_amdgcn_global_load_lds(
        (const __attribute__((address_space(1))) void*)g,
        (__attribute__((address_space(3))) void*)l, 16, 0, 0);
}

// ---------------- token build: xflat[:, 0:1024] (chunk-local rows) ----------------
__global__ __launch_bounds__(256) void build_tokens(
    const int* __restrict__ x_cat, const float* __restrict__ shared_emb,
    const float* __restrict__ emb, float* __restrict__ xflat)
{
    int idx = blockIdx.x * 256 + threadIdx.x;      // mc*1024 total
    int b = idx >> 10, r = idx & 1023;
    int c = r >> 6, d = r & 63;
    float v;
    if (d < SHARED_E) v = shared_emb[d];
    else              v = emb[((size_t)c * VOCABN + x_cat[b * NCATS + c]) * INDIVE + (d - SHARED_E)];
    xflat[(size_t)b * FLATN + r] = v;
}

// ---------------- cont projection: xflat[:, 1024:1040] ----------------
__global__ __launch_bounds__(256) void cont_proj(
    const float* __restrict__ x_cont, const float* __restrict__ cw,
    const float* __restrict__ cb, float* __restrict__ xflat)
{
    int idx = blockIdx.x * 256 + threadIdx.x;      // mc*16 total
    int b = idx >> 4, j = idx & 15;
    float acc = cb[j];
#pragma unroll
    for (int k = 0; k < 16; ++k) acc += x_cont[b * 16 + k] * cw[k * 16 + j];
    xflat[(size_t)b * FLATN + 1024 + j] = acc;
}

// ---------------- micro encoder (MFMA): 8 samples/block (16 rows), 1 wave ----------------
__global__ __launch_bounds__(64) void micro_enc_mfma(
    float* __restrict__ xflat, const short* __restrict__ wT,
    const float* __restrict__ ln1w, const float* __restrict__ ln1b,
    const float* __restrict__ ln2w, const float* __restrict__ ln2b,
    const float* __restrict__ b1, const float* __restrict__ b2)
{
    __shared__ __align__(16) float Xr[16][68];
    __shared__ __align__(16) short XN[16][72];
    __shared__ __align__(16) short KVb[16][136];  // K cols 0-63, V 64-127; later ff1
    __shared__ __align__(16) short Qb[16][72];

    int lane = threadIdx.x;
    int b0 = blockIdx.x * 8;

    {   // load: row r = s*2+t  <-  xflat[(b0+s)][t*64 + c]
        int r = lane >> 2, c0 = (lane & 3) * 16;
        const float* gx = xflat + (size_t)(b0 + (r >> 1)) * FLATN + (r & 1) * 64 + c0;
#pragma unroll
        for (int u = 0; u < 4; ++u) *(float4*)&Xr[r][c0 + u * 4] = *(const float4*)(gx + u * 4);
    }
    __syncthreads();

    int fr = lane & 15, fk = lane >> 4;
    int rb = 4 * fk;
    float prevM[2] = {0.f, 0.f};

    for (int p = 0; p < 2; ++p) {
        const short* lq  = wT + p * 49152;
        const short* lo  = lq + 12288;
        const short* lf1 = lo + 4096;
        const short* lf2 = lf1 + 16384;
        const float* l1w = ln1w + p * 64; const float* l1b = ln1b + p * 64;
        const float* l2w = ln2w + p * 64; const float* l2b = ln2b + p * 64;
        const float* fb1 = b1 + p * 256;  const float* fb2 = b2 + p * 64;

        {   // LN1 -> XN (register-blocked)
            int r = lane >> 2, c = (lane & 3) * 16;
            float4 va[4];
#pragma unroll
            for (int u = 0; u < 4; ++u) va[u] = *(const float4*)&Xr[r][c + u * 4];
            float s = 0.f, s2 = 0.f;
#pragma unroll
            for (int u = 0; u < 4; ++u) {
                s  += va[u].x + va[u].y + va[u].z + va[u].w;
                s2 += va[u].x * va[u].x + va[u].y * va[u].y + va[u].z * va[u].z + va[u].w * va[u].w;
            }
            s  += __shfl_xor(s, 1, 64);  s2 += __shfl_xor(s2, 1, 64);
            s  += __shfl_xor(s, 2, 64);  s2 += __shfl_xor(s2, 2, 64);
            float m = s * (1.f / 64.f);
            float var = s2 * (1.f / 64.f) - m * m;
            float rstd = rsqrtf(var + EPSV);
            unsigned pk[8];
#pragma unroll
            for (int u = 0; u < 4; ++u) {
                float4 wv4 = *(const float4*)(l1w + c + u * 4);
                float4 bv4 = *(const float4*)(l1b + c + u * 4);
                pk[2 * u]     = packbf((va[u].x - m) * rstd * wv4.x + bv4.x,
                                       (va[u].y - m) * rstd * wv4.y + bv4.y);
                pk[2 * u + 1] = packbf((va[u].z - m) * rstd * wv4.z + bv4.z,
                                       (va[u].w - m) * rstd * wv4.w + bv4.w);
            }
            *(uint4*)&XN[r][c]     = *(uint4*)&pk[0];
            *(uint4*)&XN[r][c + 8] = *(uint4*)&pk[4];
        }
        __syncthreads();

        {   // qkv MFMA: nf 0-3 -> Qb, nf 4-11 -> KVb
            bf16x8 a0 = *(const bf16x8*)&XN[fr][fk * 8];
            bf16x8 a1 = *(const bf16x8*)&XN[fr][fk * 8 + 32];
#pragma unroll
            for (int nf = 0; nf < 12; ++nf) {
                const short* bp = lq + (nf * 16 + fr) * 64 + fk * 8;
                bf16x8 bv0 = *(const bf16x8*)bp;
                bf16x8 bv1 = *(const bf16x8*)(bp + 32);
                f32x4 acc = {};
                acc = __builtin_amdgcn_mfma_f32_16x16x32_bf16(a0, bv0, acc, 0, 0, 0);
                acc = __builtin_amdgcn_mfma_f32_16x16x32_bf16(a1, bv1, acc, 0, 0, 0);
                int cc = nf * 16 + fr;
#pragma unroll
                for (int rr = 0; rr < 4; ++rr) {
                    if (nf < 4) Qb[rb + rr][cc] = f2bf_s(acc[rr]);
                    else        KVb[rb + rr][cc - 64] = f2bf_s(acc[rr]);
                }
            }
        }
        __syncthreads();

        {   // attention: lane = (s=lane>>3, h=(lane>>1)&3, qi=lane&1); 2 keys, registers
            int s_ = lane >> 3, h = (lane >> 1) & 3, qi = lane & 1;
            int qrow = s_ * 2 + qi;
            float q[16];
            {
                const unsigned* qp = (const unsigned*)&Qb[qrow][h * 16];
#pragma unroll
                for (int e = 0; e < 8; ++e) { q[2 * e] = bf_lo(qp[e]); q[2 * e + 1] = bf_hi(qp[e]); }
            }
            float sc[2];
#pragma unroll
            for (int j = 0; j < 2; ++j) {
                const unsigned* kp = (const unsigned*)&KVb[s_ * 2 + j][h * 16];
                float a = 0.f;
#pragma unroll
                for (int e = 0; e < 8; ++e)
                    a += q[2 * e] * bf_lo(kp[e]) + q[2 * e + 1] * bf_hi(kp[e]);
                a = a * 0.25f + prevM[j];
                prevM[j] = a;
                sc[j] = a;
            }
            float mx = fmaxf(sc[0], sc[1]);
            float e0 = expf(sc[0] - mx), e1 = expf(sc[1] - mx);
            float inv = 1.f / (e0 + e1);
            float p0 = e0 * inv, p1 = e1 * inv;
            const unsigned* v0 = (const unsigned*)&KVb[s_ * 2 + 0][64 + h * 16];
            const unsigned* v1 = (const unsigned*)&KVb[s_ * 2 + 1][64 + h * 16];
            unsigned* op = (unsigned*)&XN[qrow][h * 16];
#pragma unroll
            for (int e = 0; e < 8; ++e) {
                unsigned ua = v0[e], ub = v1[e];
                float olo = p0 * bf_lo(ua) + p1 * bf_lo(ub);
                float ohi = p0 * bf_hi(ua) + p1 * bf_hi(ub);
                op[e] = packbf(olo, ohi);
            }
        }
        __syncthreads();

        {   // out proj + residual
            bf16x8 a0 = *(const bf16x8*)&XN[fr][fk * 8];
            bf16x8 a1 = *(const bf16x8*)&XN[fr][fk * 8 + 32];
#pragma unroll
            for (int nf = 0; nf < 4; ++nf) {
                const short* bp = lo + (nf * 16 + fr) * 64 + fk * 8;
                bf16x8 bv0 = *(const bf16x8*)bp;
                bf16x8 bv1 = *(const bf16x8*)(bp + 32);
                f32x4 acc = {};
                acc = __builtin_amdgcn_mfma_f32_16x16x32_bf16(a0, bv0, acc, 0, 0, 0);
                acc = __builtin_amdgcn_mfma_f32_16x16x32_bf16(a1, bv1, acc, 0, 0, 0);
                int cc = nf * 16 + fr;
#pragma unroll
                for (int rr = 0; rr < 4; ++rr) Xr[rb + rr][cc] += acc[rr];
            }
        }
        __syncthreads();

        {   // LN2 -> XN (register-blocked)
            int r = lane >> 2, c = (lane & 3) * 16;
            float4 va[4];
#pragma unroll
            for (int u = 0; u < 4; ++u) va[u] = *(const float4*)&Xr[r][c + u * 4];
            float s = 0.f, s2 = 0.f;
#pragma unroll
            for (int u = 0; u < 4; ++u) {
                s  += va[u].x + va[u].y + va[u].z + va[u].w;
                s2 += va[u].x * va[u].x + va[u].y * va[u].y + va[u].z * va[u].z + va[u].w * va[u].w;
            }
            s  += __shfl_xor(s, 1, 64);  s2 += __shfl_xor(s2, 1, 64);
            s  += __shfl_xor(s, 2, 64);  s2 += __shfl_xor(s2, 2, 64);
            float m = s * (1.f / 64.f);
            float var = s2 * (1.f / 64.f) - m * m;
            float rstd = rsqrtf(var + EPSV);
            unsigned pk[8];
#pragma unroll
            for (int u = 0; u < 4; ++u) {
                float4 wv4 = *(const float4*)(l2w + c + u * 4);
                float4 bv4 = *(const float4*)(l2b + c + u * 4);
                pk[2 * u]     = packbf((va[u].x - m) * rstd * wv4.x + bv4.x,
                                       (va[u].y - m) * rstd * wv4.y + bv4.y);
                pk[2 * u + 1] = packbf((va[u].z - m) * rstd * wv4.z + bv4.z,
                                       (va[u].w - m) * rstd * wv4.w + bv4.w);
            }
            *(uint4*)&XN[r][c]     = *(uint4*)&pk[0];
            *(uint4*)&XN[r][c + 8] = *(uint4*)&pk[4];
        }
        __syncthreads();

        {   // FFN: ff1 halves -> KVb, ff2 acc in regs
            bf16x8 a0 = *(const bf16x8*)&XN[fr][fk * 8];
            bf16x8 a1 = *(const bf16x8*)&XN[fr][fk * 8 + 32];
            f32x4 facc[4] = {};
#pragma unroll
            for (int half = 0; half < 2; ++half) {
#pragma unroll
                for (int nf = 0; nf < 8; ++nf) {
                    int ng = half * 128 + nf * 16;
                    const short* bp = lf1 + (ng + fr) * 64 + fk * 8;
                    bf16x8 bv0 = *(const bf16x8*)bp;
                    bf16x8 bv1 = *(const bf16x8*)(bp + 32);
                    f32x4 acc = {};
                    acc = __builtin_amdgcn_mfma_f32_16x16x32_bf16(a0, bv0, acc, 0, 0, 0);
                    acc = __builtin_amdgcn_mfma_f32_16x16x32_bf16(a1, bv1, acc, 0, 0, 0);
                    int cc = nf * 16 + fr;
                    float bias1 = fb1[ng + fr];
#pragma unroll
                    for (int rr = 0; rr < 4; ++rr)
                        KVb[rb + rr][cc] = f2bf_s(gelu_f(acc[rr] + bias1));
                }
                __syncthreads();
                bf16x8 fa[4];
#pragma unroll
                for (int kf = 0; kf < 4; ++kf)
                    fa[kf] = *(const bf16x8*)&KVb[fr][kf * 32 + fk * 8];
#pragma unroll
                for (int nf = 0; nf < 4; ++nf) {
                    const short* bp = lf2 + (nf * 16 + fr) * 256 + half * 128 + fk * 8;
#pragma unroll
                    for (int kf = 0; kf < 4; ++kf)
                        facc[nf] = __builtin_amdgcn_mfma_f32_16x16x32_bf16(
                            fa[kf], *(const bf16x8*)(bp + kf * 32), facc[nf], 0, 0, 0);
                }
                __syncthreads();
            }
#pragma unroll
            for (int nf = 0; nf < 4; ++nf) {
                int cc = nf * 16 + fr;
                float bias2 = fb2[cc];
#pragma unroll
                for (int rr = 0; rr < 4; ++rr) Xr[rb + rr][cc] += facc[nf][rr] + bias2;
            }
        }
        __syncthreads();
    }

    {   // store back
        int r = lane >> 2, c0 = (lane & 3) * 16;
        float* gx = xflat + (size_t)(b0 + (r >> 1)) * FLATN + (r & 1) * 64 + c0;
#pragma unroll
        for (int u = 0; u < 4; ++u) *(float4*)(gx + u * 4) = *(const float4*)&Xr[r][c0 + u * 4];
    }
}

// ---------------- macro encoder (MFMA attn): TWO samples / block, FOUR waves ----------------
// r17: FFN barriers 4 -> 1 via 4th buffer FFb (ff1 halves write Qb/Kb/VT/FFb, no internal
// barrier); dead xflat store removed (Abf is the only consumer downstream).
__global__ __launch_bounds__(256) void macro_enc_mfma(
    float* __restrict__ xflat, __hip_bfloat16* __restrict__ Abf,
    const short* __restrict__ wT,
    const float* __restrict__ ln1w, const float* __restrict__ ln1b,
    const float* __restrict__ ln2w, const float* __restrict__ ln2b,
    const float* __restrict__ b1, const float* __restrict__ b2)
{
    __shared__ __align__(16) float Xr[32][68];
    __shared__ __align__(16) short XN[32][72];
    __shared__ __align__(16) short Qb[32][72];
    __shared__ __align__(16) short Kb[32][72];
    __shared__ __align__(16) short VT[32][72];   // VT[s2*16+d][h*16 + token]; ff1 cols 128-191
    __shared__ __align__(16) short FFb[32][72];  // ff1 cols 192-255

    int tid = threadIdx.x;
    int lane = tid & 63, w = tid >> 6;
    int b0 = blockIdx.x * 2;

    {   // load residual: 256 threads x 8 floats (32 rows)
        int r = tid >> 3, c0 = (tid & 7) * 8;
        const float* gx = xflat + (size_t)(b0 + (r >> 4)) * FLATN + (r & 15) * 64 + c0;
        *(float4*)&Xr[r][c0]     = *(const float4*)gx;
        *(float4*)&Xr[r][c0 + 4] = *(const float4*)(gx + 4);
    }
    __syncthreads();

    int fr = lane & 15, fk = lane >> 4;
    int rb = 4 * fk;
    f32x4 prevA[2] = {};   // per sample; this wave's head: h = w

    for (int p = 0; p < 2; ++p) {
        const short* lq  = wT + p * 49152;
        const short* lo  = lq + 12288;
        const short* lf1 = lo + 4096;
        const short* lf2 = lf1 + 16384;
        const float* l1w = ln1w + p * 64; const float* l1b = ln1b + p * 64;
        const float* l2w = ln2w + p * 64; const float* l2b = ln2b + p * 64;
        const float* fb1 = b1 + p * 256;  const float* fb2 = b2 + p * 64;

        {   // LN1 -> XN (register-blocked), both samples
#pragma unroll
            for (int s2i = 0; s2i < 2; ++s2i) {
                int r = s2i * 16 + w * 4 + (lane >> 4);
                int c = (lane & 15) * 4;
                float4 v = *(const float4*)&Xr[r][c];
                float s  = v.x + v.y + v.z + v.w;
                float s2 = v.x * v.x + v.y * v.y + v.z * v.z + v.w * v.w;
#pragma unroll
                for (int o = 1; o < 16; o <<= 1) {
                    s  += __shfl_xor(s, o, 64);
                    s2 += __shfl_xor(s2, o, 64);
                }
                float m = s * (1.f / 64.f);
                float var = s2 * (1.f / 64.f) - m * m;
                float rstd = rsqrtf(var + EPSV);
                float4 wv4 = *(const float4*)(l1w + c);
                float4 bv4 = *(const float4*)(l1b + c);
                unsigned pk0 = packbf((v.x - m) * rstd * wv4.x + bv4.x,
                                      (v.y - m) * rstd * wv4.y + bv4.y);
                unsigned pk1 = packbf((v.z - m) * rstd * wv4.z + bv4.z,
                                      (v.w - m) * rstd * wv4.w + bv4.w);
                unsigned long long pk = (unsigned long long)pk0 | ((unsigned long long)pk1 << 32);
                *(unsigned long long*)&XN[r][c] = pk;
            }
        }
        __syncthreads();

        {   // qkv MFMA: wave w does nf = w*3 .. w*3+2, both samples
#pragma unroll
            for (int s2i = 0; s2i < 2; ++s2i) {
                int ro = s2i * 16;
                bf16x8 a0 = *(const bf16x8*)&XN[ro + fr][fk * 8];
                bf16x8 a1 = *(const bf16x8*)&XN[ro + fr][fk * 8 + 32];
#pragma unroll
                for (int nn = 0; nn < 3; ++nn) {
                    int nf = w * 3 + nn;
                    const short* bp = lq + (nf * 16 + fr) * 64 + fk * 8;
                    bf16x8 bv0 = *(const bf16x8*)bp;
                    bf16x8 bv1 = *(const bf16x8*)(bp + 32);
                    f32x4 acc = {};
                    acc = __builtin_amdgcn_mfma_f32_16x16x32_bf16(a0, bv0, acc, 0, 0, 0);
                    acc = __builtin_amdgcn_mfma_f32_16x16x32_bf16(a1, bv1, acc, 0, 0, 0);
                    if (nf < 8) {
#pragma unroll
                        for (int rr = 0; rr < 4; ++rr) {
                            short sv = f2bf_s(acc[rr]);
                            if (nf < 4) Qb[ro + rb + rr][nf * 16 + fr] = sv;
                            else        Kb[ro + rb + rr][(nf - 4) * 16 + fr] = sv;
                        }
                    } else {
                        unsigned long long pkv =
                            (unsigned long long)packbf(acc[0], acc[1]) |
                            ((unsigned long long)packbf(acc[2], acc[3]) << 32);
                        *(unsigned long long*)&VT[ro + fr][(nf - 8) * 16 + rb] = pkv;
                    }
                }
            }
        }
        __syncthreads();

        {   // MFMA attention: wave w handles head h = w, both samples
            bf16x8 zero8 = {};
            int h = w;
#pragma unroll
            for (int s2i = 0; s2i < 2; ++s2i) {
                int ro = s2i * 16;
                bf16x8 ka = zero8, qa = zero8, va = zero8;
                if (fk < 2) {
                    ka = *(const bf16x8*)&Kb[ro + fr][h * 16 + fk * 8];
                    qa = *(const bf16x8*)&Qb[ro + fr][h * 16 + fk * 8];
                    va = *(const bf16x8*)&VT[ro + fr][h * 16 + fk * 8];
                }
                f32x4 s = {};
                s = __builtin_amdgcn_mfma_f32_16x16x32_bf16(ka, qa, s, 0, 0, 0);
#pragma unroll
                for (int rr = 0; rr < 4; ++rr) {
                    s[rr] = s[rr] * 0.25f + prevA[s2i][rr];
                    prevA[s2i][rr] = s[rr];
                }
                float m = fmaxf(fmaxf(s[0], s[1]), fmaxf(s[2], s[3]));
                m = fmaxf(m, __shfl_xor(m, 16, 64));
                m = fmaxf(m, __shfl_xor(m, 32, 64));
                float e0 = expf(s[0] - m), e1 = expf(s[1] - m);
                float e2 = expf(s[2] - m), e3 = expf(s[3] - m);
                float sum = e0 + e1 + e2 + e3;
                sum += __shfl_xor(sum, 16, 64);
                sum += __shfl_xor(sum, 32, 64);
                float inv = 1.f / sum;
                int pk0 = (int)packbf(e0 * inv, e1 * inv);
                int pk1 = (int)packbf(e2 * inv, e3 * inv);
                int s1 = fr + (((2 * fk) & 3) << 4);
                int s2 = fr + (((2 * fk + 1) & 3) << 4);
                int d0 = __shfl(pk0, s1, 64), d1 = __shfl(pk1, s1, 64);
                int d2 = __shfl(pk0, s2, 64), d3 = __shfl(pk1, s2, 64);
                bf16x8 pa = zero8;
                if (fk < 2) {
                    union { int i[4]; bf16x8 v; } u;
                    u.i[0] = d0; u.i[1] = d1; u.i[2] = d2; u.i[3] = d3;
                    pa = u.v;
                }
                f32x4 o = {};
                o = __builtin_amdgcn_mfma_f32_16x16x32_bf16(pa, va, o, 0, 0, 0);
#pragma unroll
                for (int rr = 0; rr < 4; ++rr)
                    XN[ro + 4 * fk + rr][h * 16 + fr] = f2bf_s(o[rr]);
            }
        }
        __syncthreads();

        {   // out proj + residual: wave w does nf = w, both samples
            int nf = w;
            const short* bp = lo + (nf * 16 + fr) * 64 + fk * 8;
            bf16x8 bv0 = *(const bf16x8*)bp;
            bf16x8 bv1 = *(const bf16x8*)(bp + 32);
#pragma unroll
            for (int s2i = 0; s2i < 2; ++s2i) {
                int ro = s2i * 16;
                bf16x8 a0 = *(const bf16x8*)&XN[ro + fr][fk * 8];
                bf16x8 a1 = *(const bf16x8*)&XN[ro + fr][fk * 8 + 32];
                f32x4 acc = {};
                acc = __builtin_amdgcn_mfma_f32_16x16x32_bf16(a0, bv0, acc, 0, 0, 0);
                acc = __builtin_amdgcn_mfma_f32_16x16x32_bf16(a1, bv1, acc, 0, 0, 0);
                int cc = nf * 16 + fr;
#pragma unroll
                for (int rr = 0; rr < 4; ++rr) Xr[ro + rb + rr][cc] += acc[rr];
            }
        }
        __syncthreads();

        {   // LN2 -> XN (register-blocked), both samples
#pragma unroll
            for (int s2i = 0; s2i < 2; ++s2i) {
                int r = s2i * 16 + w * 4 + (lane >> 4);
                int c = (lane & 15) * 4;
                float4 v = *(const float4*)&Xr[r][c];
                float s  = v.x + v.y + v.z + v.w;
                float s2 = v.x * v.x + v.y * v.y + v.z * v.z + v.w * v.w;
#pragma unroll
                for (int o = 1; o < 16; o <<= 1) {
                    s  += __shfl_xor(s, o, 64);
                    s2 += __shfl_xor(s2, o, 64);
                }
                float m = s * (1.f / 64.f);
                float var = s2 * (1.f / 64.f) - m * m;
                float rstd = rsqrtf(var + EPSV);
                float4 wv4 = *(const float4*)(l2w + c);
                float4 bv4 = *(const float4*)(l2b + c);
                unsigned pk0 = packbf((v.x - m) * rstd * wv4.x + bv4.x,
                                      (v.y - m) * rstd * wv4.y + bv4.y);
                unsigned pk1 = packbf((v.z - m) * rstd * wv4.z + bv4.z,
                                      (v.w - m) * rstd * wv4.w + bv4.w);
                unsigned long long pk = (unsigned long long)pk0 | ((unsigned long long)pk1 << 32);
                *(unsigned long long*)&XN[r][c] = pk;
            }
        }
        __syncthreads();

        {   // FFN: ff1 BOTH halves -> {Qb,Kb,VT,FFb} (no internal barrier), 1 barrier, ff2
            f32x4 facc[2] = {};
#pragma unroll
            for (int half = 0; half < 2; ++half) {
#pragma unroll
                for (int s2i = 0; s2i < 2; ++s2i) {
                    int ro = s2i * 16;
                    bf16x8 a0 = *(const bf16x8*)&XN[ro + fr][fk * 8];
                    bf16x8 a1 = *(const bf16x8*)&XN[ro + fr][fk * 8 + 32];
#pragma unroll
                    for (int nn = 0; nn < 2; ++nn) {
                        int nf = w * 2 + nn;
                        int ng = half * 128 + nf * 16;       // global col base
                        const short* bp = lf1 + (ng + fr) * 64 + fk * 8;
                        bf16x8 bv0 = *(const bf16x8*)bp;
                        bf16x8 bv1 = *(const bf16x8*)(bp + 32);
                        f32x4 acc = {};
                        acc = __builtin_amdgcn_mfma_f32_16x16x32_bf16(a0, bv0, acc, 0, 0, 0);
                        acc = __builtin_amdgcn_mfma_f32_16x16x32_bf16(a1, bv1, acc, 0, 0, 0);
                        int gcc = ng + fr;                   // global col of this lane
                        float bias1 = fb1[gcc];
                        int bcol = gcc & 63;
#pragma unroll
                        for (int rr = 0; rr < 4; ++rr) {
                            short sv = f2bf_s(gelu_f(acc[rr] + bias1));
                            if (gcc < 64)       Qb[ro + rb + rr][bcol] = sv;
                            else if (gcc < 128) Kb[ro + rb + rr][bcol] = sv;
                            else if (gcc < 192) VT[ro + rb + rr][bcol] = sv;
                            else                FFb[ro + rb + rr][bcol] = sv;
                        }
                    }
                }
            }
            __syncthreads();
#pragma unroll
            for (int s2i = 0; s2i < 2; ++s2i) {
                int ro = s2i * 16;
                bf16x8 fa[8];
                fa[0] = *(const bf16x8*)&Qb[ro + fr][fk * 8];
                fa[1] = *(const bf16x8*)&Qb[ro + fr][32 + fk * 8];
                fa[2] = *(const bf16x8*)&Kb[ro + fr][fk * 8];
                fa[3] = *(const bf16x8*)&Kb[ro + fr][32 + fk * 8];
                fa[4] = *(const bf16x8*)&VT[ro + fr][fk * 8];
                fa[5] = *(const bf16x8*)&VT[ro + fr][32 + fk * 8];
                fa[6] = *(const bf16x8*)&FFb[ro + fr][fk * 8];
                fa[7] = *(const bf16x8*)&FFb[ro + fr][32 + fk * 8];
                int nf = w;
                const short* bp = lf2 + (nf * 16 + fr) * 256 + fk * 8;
#pragma unroll
                for (int kf2 = 0; kf2 < 8; ++kf2)
                    facc[s2i] = __builtin_amdgcn_mfma_f32_16x16x32_bf16(
                        fa[kf2], *(const bf16x8*)(bp + kf2 * 32), facc[s2i], 0, 0, 0);
            }
            {
                int cc = w * 16 + fr;
                float bias2 = fb2[cc];
#pragma unroll
                for (int s2i = 0; s2i < 2; ++s2i)
#pragma unroll
                    for (int rr = 0; rr < 4; ++rr)
                        Xr[s2i * 16 + rb + rr][cc] += facc[s2i][rr] + bias2;
            }
        }
        __syncthreads();
    }

    // store bf16 token part of Abf (xflat store is DEAD downstream - removed)
    {
        int r = tid >> 3, c0 = (tid & 7) * 8;
        int b = b0 + (r >> 4);
        unsigned int pk[4];
#pragma unroll
        for (int e = 0; e < 4; ++e) pk[e] = packbf(Xr[r][c0 + 2 * e], Xr[r][c0 + 2 * e + 1]);
        unsigned int* ga = (unsigned int*)(Abf + (size_t)b * KP1 + (r & 15) * 64 + c0);
#pragma unroll
        for (int e = 0; e < 4; ++e) ga[e] = pk[e];
    }
    if (tid < 128) {
        int s2i = tid >> 6, c = tid & 63;
        int b = b0 + s2i;
        float v = (c < CONTN) ? xflat[(size_t)b * FLATN + 1024 + c] : 0.f;
        Abf[(size_t)b * KP1 + 1024 + c] = __float2bfloat16(v);
    }
}

// ---------------- transpose + convert: W[K][N] fp32 -> Wt[Np][Kp] bf16 (zero-padded) ----
__global__ __launch_bounds__(256) void transpose_conv(
    const float* __restrict__ src, __hip_bfloat16* __restrict__ dst,
    int K, int N, int Kp, int Np)
{
    __shared__ float T[32][33];
    int k0 = blockIdx.y * 32, n0 = blockIdx.x * 32;
    int tn = threadIdx.x & 31, tk = threadIdx.x >> 5;
#pragma unroll
    for (int r = 0; r < 4; ++r) {
        int k = k0 + tk + r * 8, n = n0 + tn;
        T[tk + r * 8][tn] = (k < K && n < N) ? src[(size_t)k * N + n] : 0.f;
    }
    __syncthreads();
#pragma unroll
    for (int r = 0; r < 4; ++r) {
        int n = n0 + tk + r * 8, k = k0 + tn;
        dst[(size_t)n * Kp + k] = __float2bfloat16(T[tn][tk + r * 8]);
    }
}

// ---------------- bf16 MFMA GEMM: m97 structure (single 32KB buffer, 2 barriers/K-step)
// + T2 both-sides swizzle (conflict-free). 3 blocks/CU (launch_bounds 3 waves/SIMD).
// MODE 1: C[M][Np] bf16 gelu via slot-swizzled LDS restage (coalesced 128B stores).
// MODE 2: partials[row][bx] = sum_cols gelu(.)*w3[col] (fused final dot).
template <int MODE>
__global__ __launch_bounds__(256, 3) void gemm_mfma(
    const __hip_bfloat16* __restrict__ A, const __hip_bfloat16* __restrict__ Bt,
    const float* __restrict__ bias, int bias_n,
    __hip_bfloat16* __restrict__ Cbf, const float* __restrict__ w3,
    float* __restrict__ partials, int Np, int Kp)
{
    __shared__ __align__(16) short LDSbuf[16384];   // 32KB: A 8192 | B 8192 shorts

    int tid = threadIdx.x;
    int lane = tid & 63, wave = tid >> 6;

    // bijective XCD swizzle (m204)
    int nbx = gridDim.x;
    int nwg = nbx * gridDim.y;
    int wgid = blockIdx.y * nbx + blockIdx.x;
    int q = nwg >> 3, r = nwg & 7;
    int xcd = wgid & 7, loc = wgid >> 3;
    int sw = (xcd < r ? xcd * (q + 1) : r * (q + 1) + (xcd - r) * q) + loc;
    int bm = (sw / nbx) * 128, bx = sw % nbx, bn = bx * 128;

    // staging addresses: lane l -> row (l>>3), k-slot (l&7)^(l>>3)  [T2 pre-swizzle]
    int lrow8 = lane >> 3;
    int lk8sw = ((lane & 7) ^ lrow8) * 8;
    const __hip_bfloat16* Ag = A  + (size_t)(bm + wave * 32 + lrow8) * Kp + lk8sw;
    const __hip_bfloat16* Bg = Bt + (size_t)(bn + wave * 32 + lrow8) * Kp + lk8sw;
    short* Al = LDSbuf + wave * 32 * 64;
    short* Bl = Al + 8192;

    int wm = (wave >> 1) * 64, wn = (wave & 1) * 64;
    int lrow = lane & 15, lk = lane >> 4;
    int key = lane & 7;                     // = (row&7) for this lane's fragment rows

    f32x4 acc[4][4] = {};
    int nt = Kp >> 6;

    for (int t = 0; t < nt; ++t) {
        int k0 = t << 6;
        __syncthreads();                    // prev tile's reads complete
#pragma unroll
        for (int it = 0; it < 4; ++it) {
            gload16(Ag + (size_t)(it * 8) * Kp + k0, Al + it * 8 * 64);
            gload16(Bg + (size_t)(it * 8) * Kp + k0, Bl + it * 8 * 64);
        }
        __syncthreads();                    // vmcnt(0) drain -> tile ready
#pragma unroll
        for (int ks = 0; ks < 2; ++ks) {
            int so = ((ks * 4 + lk) ^ key) * 8;     // swizzled slot offset (shorts)
            bf16x8 af[4], bf[4];
#pragma unroll
            for (int i = 0; i < 4; ++i) af[i] = *(const bf16x8*)(LDSbuf + (wm + i * 16 + lrow) * 64 + so);
#pragma unroll
            for (int j = 0; j < 4; ++j) bf[j] = *(const bf16x8*)(LDSbuf + 8192 + (wn + j * 16 + lrow) * 64 + so);
#pragma unroll
            for (int i = 0; i < 4; ++i)
#pragma unroll
                for (int j = 0; j < 4; ++j)
                    acc[i][j] = __builtin_amdgcn_mfma_f32_16x16x32_bf16(af[i], bf[j], acc[i][j], 0, 0, 0);
        }
    }
    __syncthreads();   // all LDS reads done; buffer reusable for epilogue

    if (MODE == 1) {
        // slot-swizzled LDS restage -> full-line coalesced bf16 stores
        short* Cs = LDSbuf;                 // [128][128] shorts = 32KB
#pragma unroll
        for (int j = 0; j < 4; ++j) {
            int cl = wn + j * 16 + lrow;
            float bv = (bn + cl < bias_n) ? bias[bn + cl] : 0.f;
#pragma unroll
            for (int i = 0; i < 4; ++i) {
#pragma unroll
                for (int rr = 0; rr < 4; ++rr) {
                    int rl = wm + i * 16 + 4 * lk + rr;
                    int pos = ((((cl >> 3) ^ (rl & 7)) << 3) | (cl & 7));
                    Cs[rl * 128 + pos] = f2bf_s(gelu_f(acc[i][j][rr] + bv));
                }
            }
        }
        __syncthreads();
        int rloc = tid >> 1, half = tid & 1;
        int4* dst = (int4*)(Cbf + (size_t)(bm + rloc) * Np + bn + half * 64);
#pragma unroll
        for (int u = 0; u < 8; ++u) {
            int slot = half * 8 + (u ^ (rloc & 7));
            dst[u] = *(const int4*)&Cs[rloc * 128 + slot * 8];
        }
    } else {
        // fused w3 reduction
        float rs[16];
#pragma unroll
        for (int t = 0; t < 16; ++t) rs[t] = 0.f;
#pragma unroll
        for (int j = 0; j < 4; ++j) {
            int gcol = bn + wn + j * 16 + lrow;
            float bv  = (gcol < bias_n) ? bias[gcol] : 0.f;
            float w3v = (gcol < H2N) ? w3[gcol] : 0.f;
#pragma unroll
            for (int i = 0; i < 4; ++i)
#pragma unroll
                for (int rr = 0; rr < 4; ++rr)
                    rs[i * 4 + rr] += gelu_f(acc[i][j][rr] + bv) * w3v;
        }
#pragma unroll
        for (int o = 1; o < 16; o <<= 1)
#pragma unroll
            for (int t = 0; t < 16; ++t) rs[t] += __shfl_xor(rs[t], o, 64);
        float* pr = (float*)LDSbuf;         // [128][2]
        if (lrow == 0) {
#pragma unroll
            for (int i = 0; i < 4; ++i)
#pragma unroll
                for (int rr = 0; rr < 4; ++rr)
                    pr[(wm + i * 16 + 4 * lk + rr) * 2 + (wave & 1)] = rs[i * 4 + rr];
        }
        __syncthreads();
        if (tid < 128)
            partials[(size_t)(bm + tid) * nbx + bx] = pr[tid * 2] + pr[tid * 2 + 1];
    }
}

// ---------------- logits = b3 + sum over N-tiles of partials ----------------
__global__ __launch_bounds__(256) void reduce_partials(
    const float* __restrict__ partials, const float* __restrict__ b3,
    float* __restrict__ out, int n, int nbx)
{
    int b = blockIdx.x * 256 + threadIdx.x;
    if (b >= n) return;
    float s = b3[0];
    for (int x = 0; x < nbx; ++x) s += partials[(size_t)b * nbx + x];
    out[b] = s;
}

extern "C" void kernel_launch(void* const* d_in, const int* in_sizes, int n_in,
                              void* d_out, int out_size, void* d_ws, size_t ws_size,
                              hipStream_t stream)
{
    const int*   x_cat      = (const int*)  d_in[0];
    const float* x_cont     = (const float*)d_in[1];
    const float* shared_emb = (const float*)d_in[2];
    const float* emb        = (const float*)d_in[3];
    const float* mi_qkv  = (const float*)d_in[4];
    const float* mi_out  = (const float*)d_in[5];
    const float* mi_ln1w = (const float*)d_in[6];
    const float* mi_ln1b = (const float*)d_in[7];
    const float* mi_ln2w = (const float*)d_in[8];
    const float* mi_ln2b = (const float*)d_in[9];
    const float* mi_w1   = (const float*)d_in[10];
    const float* mi_b1   = (const float*)d_in[11];
    const float* mi_w2   = (const float*)d_in[12];
    const float* mi_b2   = (const float*)d_in[13];
    const float* ma_qkv  = (const float*)d_in[14];
    const float* ma_out  = (const float*)d_in[15];
    const float* ma_ln1w = (const float*)d_in[16];
    const float* ma_ln1b = (const float*)d_in[17];
    const float* ma_ln2w = (const float*)d_in[18];
    const float* ma_ln2b = (const float*)d_in[19];
    const float* ma_w1   = (const float*)d_in[20];
    const float* ma_b1   = (const float*)d_in[21];
    const float* ma_w2   = (const float*)d_in[22];
    const float* ma_b2   = (const float*)d_in[23];
    const float* cont_w  = (const float*)d_in[24];
    const float* cont_b  = (const float*)d_in[25];
    const float* w1      = (const float*)d_in[26];
    const float* b1      = (const float*)d_in[27];
    const float* w2      = (const float*)d_in[28];
    const float* b2      = (const float*)d_in[29];
    const float* w3      = (const float*)d_in[30];
    const float* b3      = (const float*)d_in[31];
    float* out = (float*)d_out;

    const int NBX2 = NP2 / 128;          // 17 N-tiles in GEMM2
    const size_t ENC_SH = 4 * 49152;     // ma L0, ma L1, mi L0, mi L1
    const size_t FIXED = ((size_t)NP1 * KP1 + (size_t)NP2 * KP2 + ENC_SH) * 2;
    const size_t PER_ROW = (size_t)NP1 * 2 + (size_t)FLATN * 4 + (size_t)KP1 * 2 + (size_t)NBX2 * 4;
    size_t avail = (ws_size > FIXED) ? ws_size - FIXED : 0;
    long long chl = (long long)(avail / PER_ROW);
    int CH = (int)((chl / 128) * 128);
    if (CH > BATCH) CH = BATCH;
    if (CH < 128) CH = 128;

    char* p = (char*)d_ws;
    __hip_bfloat16* w1T = (__hip_bfloat16*)p; p += (size_t)NP1 * KP1 * 2;
    __hip_bfloat16* w2T = (__hip_bfloat16*)p; p += (size_t)NP2 * KP2 * 2;
    __hip_bfloat16* encT = (__hip_bfloat16*)p; p += ENC_SH * 2;
    __hip_bfloat16* h1  = (__hip_bfloat16*)p; p += (size_t)CH * NP1 * 2;
    float* xflat = (float*)p;                 p += (size_t)CH * FLATN * 4;
    __hip_bfloat16* Abf = (__hip_bfloat16*)p; p += (size_t)CH * KP1 * 2;
    float* partials = (float*)p;

    transpose_conv<<<dim3(NP1 / 32, KP1 / 32), 256, 0, stream>>>(w1, w1T, FLATN, H1N, KP1, NP1);
    transpose_conv<<<dim3(NP2 / 32, KP2 / 32), 256, 0, stream>>>(w2, w2T, H1N, H2N, KP2, NP2);

    // encoder weights -> bf16 [N][K] per layer: qkvT | outT | ff1T | ff2T
    const float* enc_qkv[2] = {ma_qkv, mi_qkv};
    const float* enc_out[2] = {ma_out, mi_out};
    const float* enc_w1[2]  = {ma_w1,  mi_w1};
    const float* enc_w2[2]  = {ma_w2,  mi_w2};
    for (int grp = 0; grp < 2; ++grp) {
        for (int pl = 0; pl < 2; ++pl) {
            __hip_bfloat16* base = encT + (size_t)(grp * 2 + pl) * 49152;
            transpose_conv<<<dim3(192 / 32, 64 / 32), 256, 0, stream>>>(
                enc_qkv[grp] + pl * 64 * 192, base, 64, 192, 64, 192);
            transpose_conv<<<dim3(64 / 32, 64 / 32), 256, 0, stream>>>(
                enc_out[grp] + pl * 64 * 64, base + 12288, 64, 64, 64, 64);
            transpose_conv<<<dim3(256 / 32, 64 / 32), 256, 0, stream>>>(
                enc_w1[grp] + pl * 64 * 256, base + 16384, 64, 256, 64, 256);
            transpose_conv<<<dim3(64 / 32, 256 / 32), 256, 0, stream>>>(
                enc_w2[grp] + pl * 256 * 64, base + 32768, 256, 64, 256, 64);
        }
    }

    for (int m0 = 0; m0 < BATCH; m0 += CH) {
        int mc = BATCH - m0 < CH ? BATCH - m0 : CH;   // multiple of 128

        build_tokens<<<(mc * 1024) / 256, 256, 0, stream>>>(
            x_cat + (size_t)m0 * NCATS, shared_emb, emb, xflat);
        cont_proj<<<(mc * 16) / 256, 256, 0, stream>>>(
            x_cont + (size_t)m0 * CONTN, cont_w, cont_b, xflat);
        micro_enc_mfma<<<mc / 8, 64, 0, stream>>>(
            xflat, (const short*)encT + 2 * 49152, mi_ln1w, mi_ln1b, mi_ln2w, mi_ln2b, mi_b1, mi_b2);
        macro_enc_mfma<<<mc / 2, 256, 0, stream>>>(
            xflat, Abf, (const short*)encT, ma_ln1w, ma_ln1b, ma_ln2w, ma_ln2b, ma_b1, ma_b2);

        gemm_mfma<1><<<dim3(NP1 / 128, mc / 128), 256, 0, stream>>>(
            Abf, w1T, b1, H1N, h1, nullptr, nullptr, NP1, KP1);
        gemm_mfma<2><<<dim3(NBX2, mc / 128), 256, 0, stream>>>(
            h1, w2T, b2, H2N, nullptr, w3, partials, NP2, KP2);

        reduce_partials<<<(mc + 255) / 256, 256, 0, stream>>>(partials, b3, out + m0, mc, NBX2);
    }
}